// Round 14
// baseline (160.861 us; speedup 1.0000x reference)
//
#include <hip/hip_runtime.h>

#define Bdim 2
#define Sdim 2048
#define Ddim 1024
#define Hdim 16

typedef unsigned short u16;
typedef u16 u16x8 __attribute__((ext_vector_type(8)));
typedef u16 u16x4 __attribute__((ext_vector_type(4)));
typedef unsigned u32x4 __attribute__((ext_vector_type(4)));
typedef __bf16 bf16x8 __attribute__((ext_vector_type(8)));
typedef float f32x4 __attribute__((ext_vector_type(4)));
typedef float f32x16 __attribute__((ext_vector_type(16)));

static __device__ __forceinline__ u16 f2bf(float f) {
  unsigned u = __float_as_uint(f);
  u += 0x7fffu + ((u >> 16) & 1u);
  return (u16)(u >> 16);
}
static __device__ __forceinline__ float bf2f(u16 v) {
  return __uint_as_float((unsigned)v << 16);
}
static __device__ __forceinline__ bf16x8 asbf(u16x8 v) {
  return __builtin_bit_cast(bf16x8, v);
}
static __device__ __forceinline__ f32x4 mfma16(bf16x8 a, bf16x8 b, f32x4 c) {
  return __builtin_amdgcn_mfma_f32_16x16x32_bf16(a, b, c, 0, 0, 0);
}
static __device__ __forceinline__ f32x16 mfma32(bf16x8 a, bf16x8 b, f32x16 c) {
  return __builtin_amdgcn_mfma_f32_32x32x16_bf16(a, b, c, 0, 0, 0);
}

// Fragment-tile cell index for a [rows][1024] bf16 matrix in MFMA A/B fragment
// order: cell(R,k) = ((((( (R>>7)*16 + (k>>6) )*2 + ((R>>6)&1) )*4 + ((R>>4)&3)
// )*2 + ((k>>5)&1) )*4 + ((k>>3)&3) )*16 + (R&15), each cell = 8 u16 (k&7).
// A wave's fragment load (fixed mb,kt,wg,mm,kh) is then base + lane*16B: one
// contiguous 1KB run (the r11 attention TA-fix, applied to GEMM operands).
static __device__ __forceinline__ size_t ftcell(int R, int k) {
  return ((((((size_t)(R >> 7) * 16 + (k >> 6)) * 2 + ((R >> 6) & 1)) * 4 +
            ((R >> 4) & 3)) * 2 + ((k >> 5) & 1)) * 4 + ((k >> 3) & 3)) * 16 +
         (R & 15);
}

// ---------------- cast x (f32 -> bf16) into fragment-tiled Axf ----------------
__global__ __launch_bounds__(256) void cvtx(const float* __restrict__ x,
                                            u16* __restrict__ xf) {
  int i = blockIdx.x * 256 + threadIdx.x;   // u16x8 cell id, linear over [4096][1024]
  const float4* xp = (const float4*)x;
  float4 a = xp[2 * i], b = xp[2 * i + 1];
  u16x8 o;
  o[0] = f2bf(a.x); o[1] = f2bf(a.y); o[2] = f2bf(a.z); o[3] = f2bf(a.w);
  o[4] = f2bf(b.x); o[5] = f2bf(b.y); o[6] = f2bf(b.z); o[7] = f2bf(b.w);
  int R = i >> 7, k = (i & 127) * 8;
  ((u16x8*)xf)[ftcell(R, k)] = o;
}

// ---------- transpose + cast W [K][N] f32 -> fragment-tiled WT (N-major rows) ----------
__global__ __launch_bounds__(256) void transw(
    const float* __restrict__ W0, const float* __restrict__ W1,
    const float* __restrict__ W2, const float* __restrict__ W3,
    u16* __restrict__ T0, u16* __restrict__ T1,
    u16* __restrict__ T2, u16* __restrict__ T3) {
  const float* W = blockIdx.z == 0 ? W0 : blockIdx.z == 1 ? W1 : blockIdx.z == 2 ? W2 : W3;
  u16* T = blockIdx.z == 0 ? T0 : blockIdx.z == 1 ? T1 : blockIdx.z == 2 ? T2 : T3;
  __shared__ float tile[32][33];
  const int t = threadIdx.x;
  const int k0 = blockIdx.x * 32, n0 = blockIdx.y * 32;
  const int r = t >> 3, cq = (t & 7) * 4;
  float4 v = *(const float4*)(W + (size_t)(k0 + r) * Ddim + n0 + cq);
  tile[r][cq] = v.x; tile[r][cq + 1] = v.y; tile[r][cq + 2] = v.z; tile[r][cq + 3] = v.w;
  __syncthreads();
  u16x4 ov;
  ov[0] = f2bf(tile[cq][r]);
  ov[1] = f2bf(tile[cq + 1][r]);
  ov[2] = f2bf(tile[cq + 2][r]);
  ov[3] = f2bf(tile[cq + 3][r]);
  int n = n0 + r, k = k0 + cq;       // Bt row n, cols k..k+3 (within one cell)
  *(u16x4*)(T + ftcell(n, k) * 8 + (k & 7)) = ov;
}

// -------- transpose V [B,S,D] -> fragment-tiled Vt[bh][kt][c][dh] (attn layout) --------
__global__ __launch_bounds__(256) void vtrans(const u16* __restrict__ V,
                                              u16* __restrict__ Vt) {
  __shared__ u16 tile[32][72];
  const int t = threadIdx.x;
  const int s0 = blockIdx.x * 32;
  const int bh = blockIdx.y, b = bh >> 4, h = bh & 15;
  {
    int sl = t >> 3, dq = (t & 7) * 8;
    u16x8 v = *(const u16x8*)(V + (size_t)(b * Sdim + s0 + sl) * Ddim + h * 64 + dq);
    *(u16x8*)(&tile[sl][dq]) = v;
  }
  __syncthreads();
  {
    int dl = t >> 2, sq = (t & 3) * 8;
    u16x8 v;
#pragma unroll
    for (int i = 0; i < 8; i++) v[i] = tile[sq + i][dl];
    int s = s0 + sq;
    int kt = s >> 6, c = (s >> 3) & 7;
    *(u16x8*)(Vt + ((((size_t)bh * 32 + kt) * 8 + c) * 64 + dl) * 8) = v;
  }
}

// -------- tile K into fragment-ordered Kt[bh][kt][c][row] (attn layout) --------
__global__ __launch_bounds__(256) void tilek(const u16* __restrict__ K,
                                             u16* __restrict__ Kt) {
  int tid = blockIdx.x * 256 + threadIdx.x;  // 0 .. 524287
  int row = tid & 63;
  int c = (tid >> 6) & 7;
  int kt = (tid >> 9) & 31;
  int bh = tid >> 14;
  int b = bh >> 4, h = bh & 15;
  u16x8 kc = *(const u16x8*)(K + (size_t)(b * Sdim + kt * 64 + row) * Ddim + h * 64 + c * 8);
  ((u16x8*)Kt)[tid] = kc;
}

// ---------------- 128x128 bf16 MFMA GEMM — LDS-FREE, fragment-tiled operands ----------------
// A (Axf) and Bt (Btf) are pre-permuted into fragment order, so every operand
// load is base + lane*16B: contiguous 1KB, 8 sequential lines (vs 8 scattered
// 2KB-stride lines in the staged version -> the r13-profiled TA bottleneck).
// No LDS, no barriers: 16 waves/CU (VGPR<=128) free-run and hide L2 latency.
// Merged-N launch: blockIdx.y = (z<<3)|n-tile.
template <bool F32OUT>
__global__ __launch_bounds__(256, 4) void gemm128(
    const u16* __restrict__ A,
    const u16* __restrict__ Bt0, const u16* __restrict__ Bt1, const u16* __restrict__ Bt2,
    void* __restrict__ C0v, void* __restrict__ C1v, void* __restrict__ C2v) {
  const int zz = blockIdx.y >> 3;
  const u16* Bt = (zz == 0) ? Bt0 : (zz == 1) ? Bt1 : Bt2;
  void* Cv = (zz == 0) ? C0v : (zz == 1) ? C1v : C2v;

  const int t = threadIdx.x;
  const int lane = t & 63, w = t >> 6;
  const int wm = w >> 1, wn = w & 1;
  const int c = lane & 15, g = lane >> 4;
  const int mb = blockIdx.x, nb = blockIdx.y & 7;
  const float oscale = (!F32OUT && zz == 0) ? 0.125f : 1.0f;

  const f32x4 zv = {0.f, 0.f, 0.f, 0.f};
  f32x4 acc[4][4];
#pragma unroll
  for (int m = 0; m < 4; m++)
#pragma unroll
    for (int n = 0; n < 4; n++) acc[m][n] = zv;

  // u16 base of fragment (X*64 + lane)*8 with X = (((blk*16+kt)*2+wg)*4+mm)*2+kh
  const u16* Abase = A + (size_t)lane * 8;
  const u16* Bbase = Bt + (size_t)lane * 8;
  for (int kt = 0; kt < 16; ++kt) {
#pragma unroll
    for (int kh = 0; kh < 2; kh++) {
      bf16x8 af[4], bfr[4];
#pragma unroll
      for (int m = 0; m < 4; m++) {
        size_t X = ((((size_t)mb * 16 + kt) * 2 + wm) * 4 + m) * 2 + kh;
        af[m] = asbf(*(const u16x8*)(Abase + X * 512));
      }
#pragma unroll
      for (int n = 0; n < 4; n++) {
        size_t Y = ((((size_t)nb * 16 + kt) * 2 + wn) * 4 + n) * 2 + kh;
        bfr[n] = asbf(*(const u16x8*)(Bbase + Y * 512));
      }
#pragma unroll
      for (int m = 0; m < 4; m++)
#pragma unroll
        for (int n = 0; n < 4; n++) acc[m][n] = mfma16(af[m], bfr[n], acc[m][n]);
    }
  }
  // epilogue: C/D layout col=lane&15, row=4*(lane>>4)+r  [measured m89/m91]
#pragma unroll
  for (int m = 0; m < 4; m++)
#pragma unroll
    for (int n = 0; n < 4; n++)
#pragma unroll
      for (int r = 0; r < 4; r++) {
        int row = mb * 128 + wm * 64 + m * 16 + 4 * g + r;
        int col = nb * 128 + wn * 64 + n * 16 + c;
        if (F32OUT)
          ((float*)Cv)[(size_t)row * 1024 + col] = acc[m][n][r];
        else
          ((u16*)Cv)[(size_t)row * 1024 + col] = f2bf(acc[m][n][r] * oscale);
      }
}

// ---------------- flash attention: tiled K/V + KV-split (r13-verified) ----------------
// NS>1 writes unnormalized bf16 O-partial + (m,l); attn_combine merges.
// NS==1 path writes O in Axf fragment-tiled layout (feeds the LDS-free Wo gemm).
__global__ __launch_bounds__(64, 4) void attn_kernel(
    const u16* __restrict__ Q, const u16* __restrict__ Kt,
    const u16* __restrict__ Vt, const int* __restrict__ vlen,
    u16* __restrict__ O, u16* __restrict__ Opart, float2* __restrict__ mlp) {
  __shared__ u16 ot[32][72];
  const int lane = threadIdx.x;
  const int q = lane & 31, hi = lane >> 5;
  const int bh = blockIdx.y, b = bh >> 4, h = bh & 15;
  const int q0 = blockIdx.x * 32;
  const int nv = vlen[b];
  const int NS = gridDim.z, z = blockIdx.z;

  bf16x8 qf[4];
  {
    const u16* qp = Q + (size_t)(b * Sdim + q0 + q) * Ddim + h * 64 + hi * 8;
#pragma unroll
    for (int s = 0; s < 4; s++) qf[s] = asbf(*(const u16x8*)(qp + s * 16));
  }

  f32x16 o0, o1;
#pragma unroll
  for (int r = 0; r < 16; r++) { o0[r] = 0.f; o1[r] = 0.f; }
  float m = -3.0e38f, l = 0.f;

  const int nt = (nv + 63) >> 6;
  const int chunk = (nt + NS - 1) / NS;
  const int t0 = z * chunk;
  const int t1 = min(nt, t0 + chunk);
  for (int kt = t0; kt < t1; ++kt) {
    const int k0 = kt * 64;
    const u16* Ktile = Kt + ((size_t)bh * 32 + kt) * 4096;
    const u16* Vtile = Vt + ((size_t)bh * 32 + kt) * 4096;
    f32x16 sc[2];
#pragma unroll
    for (int kb = 0; kb < 2; kb++) {
      f32x16 acc;
#pragma unroll
      for (int r = 0; r < 16; r++) acc[r] = 0.f;
#pragma unroll
      for (int s = 0; s < 4; s++) {
        bf16x8 kf = asbf(*(const u16x8*)(Ktile + (2 * s + hi) * 512 + (kb * 32 + q) * 8));
        acc = mfma32(kf, qf[s], acc);
      }
      sc[kb] = acc;
    }
    if (k0 + 64 > nv) {
#pragma unroll
      for (int kb = 0; kb < 2; kb++)
#pragma unroll
        for (int r = 0; r < 16; r++) {
          int key = k0 + kb * 32 + (r & 3) + 8 * (r >> 2) + 4 * hi;
          if (key >= nv) sc[kb][r] = -1e30f;
        }
    }
    float mx[16];
#pragma unroll
    for (int r = 0; r < 16; r++) mx[r] = fmaxf(sc[0][r], sc[1][r]);
#pragma unroll
    for (int st = 8; st > 0; st >>= 1)
#pragma unroll
      for (int r = 0; r < st; r++) mx[r] = fmaxf(mx[r], mx[r + st]);
    float tm = fmaxf(mx[0], __shfl_xor(mx[0], 32));
    if (!__all(tm <= m + 8.f)) {
      float mn = fmaxf(m, tm);
      float al = __expf(m - mn);
#pragma unroll
      for (int r = 0; r < 16; r++) { o0[r] *= al; o1[r] *= al; }
      l *= al;
      m = mn;
    }
    unsigned pw[4][4];
    float s0 = 0.f, s1 = 0.f, s2 = 0.f, s3 = 0.f;
#pragma unroll
    for (int kb = 0; kb < 2; kb++)
#pragma unroll
      for (int hh = 0; hh < 2; hh++)
#pragma unroll
        for (int wi = 0; wi < 4; wi++) {
          float e0 = __expf(sc[kb][hh * 8 + wi * 2] - m);
          float e1 = __expf(sc[kb][hh * 8 + wi * 2 + 1] - m);
          if (wi == 0) s0 += e0 + e1;
          else if (wi == 1) s1 += e0 + e1;
          else if (wi == 2) s2 += e0 + e1;
          else s3 += e0 + e1;
          asm("v_cvt_pk_bf16_f32 %0, %1, %2"
              : "=v"(pw[kb * 2 + hh][wi]) : "v"(e0), "v"(e1));
        }
    float ssum = (s0 + s1) + (s2 + s3);
    ssum += __shfl_xor(ssum, 32);
    l += ssum;
#pragma unroll
    for (int f = 0; f < 4; f++) {
      asm("v_permlane32_swap_b32 %0, %1" : "+v"(pw[f][0]), "+v"(pw[f][2]));
      asm("v_permlane32_swap_b32 %0, %1" : "+v"(pw[f][1]), "+v"(pw[f][3]));
    }
#pragma unroll
    for (int f = 0; f < 4; f++) {
      u32x4 wv = {pw[f][0], pw[f][1], pw[f][2], pw[f][3]};
      bf16x8 pa = __builtin_bit_cast(bf16x8, wv);
      bf16x8 va = asbf(*(const u16x8*)(Vtile + (2 * f + hi) * 512 + q * 8));
      bf16x8 vb = asbf(*(const u16x8*)(Vtile + (2 * f + hi) * 512 + (32 + q) * 8));
      o0 = mfma32(va, pa, o0);
      o1 = mfma32(vb, pa, o1);
    }
  }
  const float scale = (NS == 1) ? (1.f / l) : 1.f;
#pragma unroll
  for (int r = 0; r < 16; r++) {
    const int dh = (r & 3) + 8 * (r >> 2) + 4 * hi;
    ot[q][dh] = f2bf(o0[r] * scale);
    ot[q][32 + dh] = f2bf(o1[r] * scale);
  }
  asm volatile("s_waitcnt lgkmcnt(0)" ::: "memory");
  __builtin_amdgcn_sched_barrier(0);
  if (NS == 1) {
    int R = b * Sdim + q0 + q;
#pragma unroll
    for (int j = 0; j < 4; j++) {
      int k = h * 64 + hi * 32 + j * 8;
      ((u16x8*)O)[ftcell(R, k)] = *(const u16x8*)(&ot[q][hi * 32 + j * 8]);
    }
  } else {
    u16* op = Opart + ((size_t)(z * 32 + bh) * Sdim + q0 + q) * 64 + hi * 32;
#pragma unroll
    for (int j = 0; j < 4; j++)
      *(u16x8*)(op + j * 8) = *(const u16x8*)(&ot[q][hi * 32 + j * 8]);
    if (hi == 0)
      mlp[(size_t)(z * 32 + bh) * Sdim + q0 + q] = make_float2(m, l);
  }
}

// ---- combine NS split partials -> O in Axf fragment-tiled layout (Wo gemm A) ----
template <int NS>
__global__ __launch_bounds__(256) void attn_combine(
    const u16* __restrict__ Opart, const float2* __restrict__ mlp,
    u16* __restrict__ O) {
  const int t = threadIdx.x;
  const int bh = blockIdx.y, b = bh >> 4, h = bh & 15;
  const int q = blockIdx.x * 32 + (t >> 3);
  const int d0 = (t & 7) * 8;
  float2 ml[NS];
  float M = -3.0e38f;
#pragma unroll
  for (int z = 0; z < NS; z++) {
    ml[z] = mlp[(size_t)(z * 32 + bh) * Sdim + q];
    M = fmaxf(M, ml[z].x);
  }
  float acc[8];
#pragma unroll
  for (int i = 0; i < 8; i++) acc[i] = 0.f;
  float wsum = 0.f;
#pragma unroll
  for (int z = 0; z < NS; z++) {
    float w = __expf(ml[z].x - M);
    wsum += w * ml[z].y;
    u16x8 ov = *(const u16x8*)(Opart + ((size_t)(z * 32 + bh) * Sdim + q) * 64 + d0);
#pragma unroll
    for (int i = 0; i < 8; i++) acc[i] += w * bf2f(ov[i]);
  }
  const float inv = 1.f / wsum;
  u16x8 res;
#pragma unroll
  for (int i = 0; i < 8; i++) res[i] = f2bf(acc[i] * inv);
  int R = b * Sdim + q, k = h * 64 + d0;
  ((u16x8*)O)[ftcell(R, k)] = res;
}

extern "C" void kernel_launch(void* const* d_in, const int* in_sizes, int n_in,
                              void* d_out, int out_size, void* d_ws, size_t ws_size,
                              hipStream_t stream) {
  const float* x = (const float*)d_in[0];
  const float* Wq = (const float*)d_in[1];
  const float* Wk = (const float*)d_in[2];
  const float* Wv = (const float*)d_in[3];
  const float* Wo = (const float*)d_in[4];
  const int* vl = (const int*)d_in[5];
  float* out = (float*)d_out;

  char* ws = (char*)d_ws;
  const size_t SZ_X = (size_t)Bdim * Sdim * Ddim * sizeof(u16);  // 8 MB
  const size_t SZ_W = (size_t)Ddim * Ddim * sizeof(u16);         // 2 MB
  u16* xf = (u16*)ws; ws += SZ_X;   // fragment-tiled x
  u16* WqT = (u16*)ws; ws += SZ_W;  // fragment-tiled weights
  u16* WkT = (u16*)ws; ws += SZ_W;
  u16* WvT = (u16*)ws; ws += SZ_W;
  u16* WoT = (u16*)ws; ws += SZ_W;
  u16* Qb = (u16*)ws; ws += SZ_X;   // row-major gemm outputs
  u16* Kb = (u16*)ws; ws += SZ_X;
  u16* Vb = (u16*)ws; ws += SZ_X;
  u16* Obf = (u16*)ws; ws += SZ_X;  // fragment-tiled attention output
  u16* Ktb = (u16*)ws; ws += SZ_X;  // fragment-tiled K (attn)
  u16* Vtb = (u16*)ws; ws += SZ_X;  // fragment-tiled V^T (attn)

  const size_t PER_SPLIT = (size_t)Bdim * Hdim * Sdim * 64 * sizeof(u16) +
                           (size_t)Bdim * Hdim * Sdim * sizeof(float2);
  size_t used = (size_t)(ws - (char*)d_ws);
  size_t avail = (ws_size > used) ? ws_size - used : 0;
  int NS = (avail >= 4 * PER_SPLIT) ? 4 : (avail >= 2 * PER_SPLIT) ? 2 : 1;
  u16* Opart = (u16*)ws;
  float2* mlp = (float2*)(ws + (size_t)NS * Bdim * Hdim * Sdim * 64 * sizeof(u16));

  cvtx<<<dim3((Bdim * Sdim * Ddim) / (8 * 256)), 256, 0, stream>>>(x, xf);
  transw<<<dim3(32, 32, 4), 256, 0, stream>>>(Wq, Wk, Wv, Wo, WqT, WkT, WvT, WoT);
  gemm128<false><<<dim3(32, 24), 256, 0, stream>>>(xf, WqT, WkT, WvT, Qb, Kb, Vb);
  vtrans<<<dim3(Sdim / 32, Bdim * Hdim), 256, 0, stream>>>(Vb, Vtb);
  tilek<<<dim3((Bdim * Sdim * Ddim / 8) / 256), 256, 0, stream>>>(Kb, Ktb);
  attn_kernel<<<dim3(Sdim / 32, Bdim * Hdim, NS), 64, 0, stream>>>(Qb, Ktb, Vtb, vl, Obf,
                                                                   Opart, mlp);
  if (NS == 4)
    attn_combine<4><<<dim3(Sdim / 32, Bdim * Hdim), 256, 0, stream>>>(Opart, mlp, Obf);
  else if (NS == 2)
    attn_combine<2><<<dim3(Sdim / 32, Bdim * Hdim), 256, 0, stream>>>(Opart, mlp, Obf);
  gemm128<true><<<dim3(32, 8), 256, 0, stream>>>(Obf, WoT, WoT, WoT, out, out, out);
}

// Round 15
// 126.577 us; speedup vs baseline: 1.2709x; 1.2709x over previous
//
#include <hip/hip_runtime.h>

#define Bdim 2
#define Sdim 2048
#define Ddim 1024
#define Hdim 16

typedef unsigned short u16;
typedef u16 u16x8 __attribute__((ext_vector_type(8)));
typedef u16 u16x4 __attribute__((ext_vector_type(4)));
typedef unsigned u32x4 __attribute__((ext_vector_type(4)));
typedef __bf16 bf16x8 __attribute__((ext_vector_type(8)));
typedef float f32x4 __attribute__((ext_vector_type(4)));
typedef float f32x16 __attribute__((ext_vector_type(16)));

static __device__ __forceinline__ u16 f2bf(float f) {
  unsigned u = __float_as_uint(f);
  u += 0x7fffu + ((u >> 16) & 1u);
  return (u16)(u >> 16);
}
static __device__ __forceinline__ float bf2f(u16 v) {
  return __uint_as_float((unsigned)v << 16);
}
static __device__ __forceinline__ bf16x8 asbf(u16x8 v) {
  return __builtin_bit_cast(bf16x8, v);
}
static __device__ __forceinline__ f32x4 mfma16(bf16x8 a, bf16x8 b, f32x4 c) {
  return __builtin_amdgcn_mfma_f32_16x16x32_bf16(a, b, c, 0, 0, 0);
}
static __device__ __forceinline__ f32x16 mfma32(bf16x8 a, bf16x8 b, f32x16 c) {
  return __builtin_amdgcn_mfma_f32_32x32x16_bf16(a, b, c, 0, 0, 0);
}

// ---------------- cast x (f32 -> bf16), 8 elems/thread ----------------
__global__ __launch_bounds__(256) void cvtx(const float* __restrict__ x,
                                            u16* __restrict__ xb) {
  int i = blockIdx.x * 256 + threadIdx.x;
  const float4* xp = (const float4*)x;
  float4 a = xp[2 * i], b = xp[2 * i + 1];
  u16x8 o;
  o[0] = f2bf(a.x); o[1] = f2bf(a.y); o[2] = f2bf(a.z); o[3] = f2bf(a.w);
  o[4] = f2bf(b.x); o[5] = f2bf(b.y); o[6] = f2bf(b.z); o[7] = f2bf(b.w);
  ((u16x8*)xb)[i] = o;
}

// ---------------- transpose + cast W [K][N] f32 -> WT [N][K] bf16 ----------------
__global__ __launch_bounds__(256) void transw(
    const float* __restrict__ W0, const float* __restrict__ W1,
    const float* __restrict__ W2, const float* __restrict__ W3,
    u16* __restrict__ T0, u16* __restrict__ T1,
    u16* __restrict__ T2, u16* __restrict__ T3) {
  const float* W = blockIdx.z == 0 ? W0 : blockIdx.z == 1 ? W1 : blockIdx.z == 2 ? W2 : W3;
  u16* T = blockIdx.z == 0 ? T0 : blockIdx.z == 1 ? T1 : blockIdx.z == 2 ? T2 : T3;
  __shared__ float tile[32][33];
  const int t = threadIdx.x;
  const int k0 = blockIdx.x * 32, n0 = blockIdx.y * 32;
  const int r = t >> 3, cq = (t & 7) * 4;
  float4 v = *(const float4*)(W + (size_t)(k0 + r) * Ddim + n0 + cq);
  tile[r][cq] = v.x; tile[r][cq + 1] = v.y; tile[r][cq + 2] = v.z; tile[r][cq + 3] = v.w;
  __syncthreads();
  u16x4 ov;
  ov[0] = f2bf(tile[cq][r]);
  ov[1] = f2bf(tile[cq + 1][r]);
  ov[2] = f2bf(tile[cq + 2][r]);
  ov[3] = f2bf(tile[cq + 3][r]);
  *(u16x4*)(T + (size_t)(n0 + r) * Ddim + k0 + cq) = ov;
}

// -------- transpose V [B,S,D] -> fragment-tiled Vt[bh][kt][c][dh] --------
__global__ __launch_bounds__(256) void vtrans(const u16* __restrict__ V,
                                              u16* __restrict__ Vt) {
  __shared__ u16 tile[32][72];
  const int t = threadIdx.x;
  const int s0 = blockIdx.x * 32;
  const int bh = blockIdx.y, b = bh >> 4, h = bh & 15;
  {
    int sl = t >> 3, dq = (t & 7) * 8;
    u16x8 v = *(const u16x8*)(V + (size_t)(b * Sdim + s0 + sl) * Ddim + h * 64 + dq);
    *(u16x8*)(&tile[sl][dq]) = v;
  }
  __syncthreads();
  {
    int dl = t >> 2, sq = (t & 3) * 8;
    u16x8 v;
#pragma unroll
    for (int i = 0; i < 8; i++) v[i] = tile[sq + i][dl];
    int s = s0 + sq;
    int kt = s >> 6, c = (s >> 3) & 7;
    *(u16x8*)(Vt + ((((size_t)bh * 32 + kt) * 8 + c) * 64 + dl) * 8) = v;
  }
}

// -------- tile K into fragment-ordered Kt[bh][kt][c][row] --------
__global__ __launch_bounds__(256) void tilek(const u16* __restrict__ K,
                                             u16* __restrict__ Kt) {
  int tid = blockIdx.x * 256 + threadIdx.x;  // 0 .. 524287
  int row = tid & 63;
  int c = (tid >> 6) & 7;
  int kt = (tid >> 9) & 31;
  int bh = tid >> 14;
  int b = bh >> 4, h = bh & 15;
  u16x8 kc = *(const u16x8*)(K + (size_t)(b * Sdim + kt * 64 + row) * Ddim + h * 64 + c * 8);
  ((u16x8*)Kt)[tid] = kc;
}

// ---------------- 128x128 bf16 MFMA GEMM — r13 staging + issue-early/write-late (T14) ----------------
// r13's structure put the full global-load latency naked on the per-K-step
// critical path (stage+wait -> barrier -> MFMA -> barrier). Here the loads for
// step kt+1 are ISSUED before the MFMA phase of step kt (latency hides under
// ~400cy of ds_read+MFMA); the vmcnt wait + ds_write land after the barrier.
// Same swizzle, same 2 barriers/step, single 32KB LDS buffer, +32 VGPR in-flight.
template <bool F32OUT>
__global__ __launch_bounds__(256) void gemm128(
    const u16* __restrict__ A,
    const u16* __restrict__ Bt0, const u16* __restrict__ Bt1, const u16* __restrict__ Bt2,
    void* __restrict__ C0v, void* __restrict__ C1v, void* __restrict__ C2v) {
  __shared__ u16 As[128 * 64];
  __shared__ u16 Bs[128 * 64];
  const int zz = blockIdx.y >> 3;
  const u16* Bt = (zz == 0) ? Bt0 : (zz == 1) ? Bt1 : Bt2;
  void* Cv = (zz == 0) ? C0v : (zz == 1) ? C1v : C2v;

  const int t = threadIdx.x;
  const int lane = t & 63, w = t >> 6;
  const int wm = w >> 1, wn = w & 1;
  const int c = lane & 15, g = lane >> 4;
  const int m0 = blockIdx.x * 128, n0 = (blockIdx.y & 7) * 128;
  const float oscale = (!F32OUT && zz == 0) ? 0.125f : 1.0f;

  const f32x4 zv = {0.f, 0.f, 0.f, 0.f};
  f32x4 acc[4][4];
#pragma unroll
  for (int m = 0; m < 4; m++)
#pragma unroll
    for (int n = 0; n < 4; n++) acc[m][n] = zv;

  // staging chunk map: idx = t + 256*i -> row = idx>>3, ch = idx&7 (8 chunks/row)
  u16x8 ra[4], rb[4];
#pragma unroll
  for (int i = 0; i < 4; i++) {  // prologue: load kt=0
    int idx = t + 256 * i;
    int row = idx >> 3, ch = idx & 7;
    ra[i] = *(const u16x8*)(A + (size_t)(m0 + row) * 1024 + ch * 8);
    rb[i] = *(const u16x8*)(Bt + (size_t)(n0 + row) * 1024 + ch * 8);
  }
#pragma unroll
  for (int i = 0; i < 4; i++) {
    int idx = t + 256 * i;
    int row = idx >> 3, ch = idx & 7;
    int sw = (ch ^ (row & 7)) * 8;
    *(u16x8*)(As + row * 64 + sw) = ra[i];
    *(u16x8*)(Bs + row * 64 + sw) = rb[i];
  }
  __syncthreads();

  for (int kt = 0; kt < 1024; kt += 64) {
    const bool more = (kt + 64) < 1024;
    if (more) {  // issue next-tile loads NOW; latency hides under MFMA phase
#pragma unroll
      for (int i = 0; i < 4; i++) {
        int idx = t + 256 * i;
        int row = idx >> 3, ch = idx & 7;
        ra[i] = *(const u16x8*)(A + (size_t)(m0 + row) * 1024 + kt + 64 + ch * 8);
        rb[i] = *(const u16x8*)(Bt + (size_t)(n0 + row) * 1024 + kt + 64 + ch * 8);
      }
    }
    // MFMA phase on current LDS tile
#pragma unroll
    for (int kh = 0; kh < 2; kh++) {
      bf16x8 af[4], bfr[4];
#pragma unroll
      for (int m = 0; m < 4; m++) {
        int row = wm * 64 + m * 16 + c;
        int chr = kh * 4 + g;
        af[m] = asbf(*(const u16x8*)(As + row * 64 + ((chr ^ (row & 7)) * 8)));
      }
#pragma unroll
      for (int n = 0; n < 4; n++) {
        int row = wn * 64 + n * 16 + c;
        int chr = kh * 4 + g;
        bfr[n] = asbf(*(const u16x8*)(Bs + row * 64 + ((chr ^ (row & 7)) * 8)));
      }
#pragma unroll
      for (int m = 0; m < 4; m++)
#pragma unroll
        for (int n = 0; n < 4; n++) acc[m][n] = mfma16(af[m], bfr[n], acc[m][n]);
    }
    if (more) {
      __syncthreads();  // all waves done reading current tile
#pragma unroll
      for (int i = 0; i < 4; i++) {  // publish prefetched tile (vmcnt wait lands here)
        int idx = t + 256 * i;
        int row = idx >> 3, ch = idx & 7;
        int sw = (ch ^ (row & 7)) * 8;
        *(u16x8*)(As + row * 64 + sw) = ra[i];
        *(u16x8*)(Bs + row * 64 + sw) = rb[i];
      }
      __syncthreads();  // writes visible
    }
  }
  // epilogue: C/D layout col=lane&15, row=4*(lane>>4)+r  [measured m89/m91]
#pragma unroll
  for (int m = 0; m < 4; m++)
#pragma unroll
    for (int n = 0; n < 4; n++)
#pragma unroll
      for (int r = 0; r < 4; r++) {
        int row = m0 + wm * 64 + m * 16 + 4 * g + r;
        int col = n0 + wn * 64 + n * 16 + c;
        if (F32OUT)
          ((float*)Cv)[(size_t)row * 1024 + col] = acc[m][n][r];
        else
          ((u16*)Cv)[(size_t)row * 1024 + col] = f2bf(acc[m][n][r] * oscale);
      }
}

// ---------------- flash attention: tiled K/V + KV-split (r13-verified) ----------------
__global__ __launch_bounds__(64, 4) void attn_kernel(
    const u16* __restrict__ Q, const u16* __restrict__ Kt,
    const u16* __restrict__ Vt, const int* __restrict__ vlen,
    u16* __restrict__ O, u16* __restrict__ Opart, float2* __restrict__ mlp) {
  __shared__ u16 ot[32][72];
  const int lane = threadIdx.x;
  const int q = lane & 31, hi = lane >> 5;
  const int bh = blockIdx.y, b = bh >> 4, h = bh & 15;
  const int q0 = blockIdx.x * 32;
  const int nv = vlen[b];
  const int NS = gridDim.z, z = blockIdx.z;

  bf16x8 qf[4];
  {
    const u16* qp = Q + (size_t)(b * Sdim + q0 + q) * Ddim + h * 64 + hi * 8;
#pragma unroll
    for (int s = 0; s < 4; s++) qf[s] = asbf(*(const u16x8*)(qp + s * 16));
  }

  f32x16 o0, o1;
#pragma unroll
  for (int r = 0; r < 16; r++) { o0[r] = 0.f; o1[r] = 0.f; }
  float m = -3.0e38f, l = 0.f;

  const int nt = (nv + 63) >> 6;
  const int chunk = (nt + NS - 1) / NS;
  const int t0 = z * chunk;
  const int t1 = min(nt, t0 + chunk);
  for (int kt = t0; kt < t1; ++kt) {
    const int k0 = kt * 64;
    const u16* Ktile = Kt + ((size_t)bh * 32 + kt) * 4096;
    const u16* Vtile = Vt + ((size_t)bh * 32 + kt) * 4096;
    f32x16 sc[2];
#pragma unroll
    for (int kb = 0; kb < 2; kb++) {
      f32x16 acc;
#pragma unroll
      for (int r = 0; r < 16; r++) acc[r] = 0.f;
#pragma unroll
      for (int s = 0; s < 4; s++) {
        bf16x8 kf = asbf(*(const u16x8*)(Ktile + (2 * s + hi) * 512 + (kb * 32 + q) * 8));
        acc = mfma32(kf, qf[s], acc);
      }
      sc[kb] = acc;
    }
    if (k0 + 64 > nv) {
#pragma unroll
      for (int kb = 0; kb < 2; kb++)
#pragma unroll
        for (int r = 0; r < 16; r++) {
          int key = k0 + kb * 32 + (r & 3) + 8 * (r >> 2) + 4 * hi;
          if (key >= nv) sc[kb][r] = -1e30f;
        }
    }
    float mx[16];
#pragma unroll
    for (int r = 0; r < 16; r++) mx[r] = fmaxf(sc[0][r], sc[1][r]);
#pragma unroll
    for (int st = 8; st > 0; st >>= 1)
#pragma unroll
      for (int r = 0; r < st; r++) mx[r] = fmaxf(mx[r], mx[r + st]);
    float tm = fmaxf(mx[0], __shfl_xor(mx[0], 32));
    if (!__all(tm <= m + 8.f)) {
      float mn = fmaxf(m, tm);
      float al = __expf(m - mn);
#pragma unroll
      for (int r = 0; r < 16; r++) { o0[r] *= al; o1[r] *= al; }
      l *= al;
      m = mn;
    }
    unsigned pw[4][4];
    float s0 = 0.f, s1 = 0.f, s2 = 0.f, s3 = 0.f;
#pragma unroll
    for (int kb = 0; kb < 2; kb++)
#pragma unroll
      for (int hh = 0; hh < 2; hh++)
#pragma unroll
        for (int wi = 0; wi < 4; wi++) {
          float e0 = __expf(sc[kb][hh * 8 + wi * 2] - m);
          float e1 = __expf(sc[kb][hh * 8 + wi * 2 + 1] - m);
          if (wi == 0) s0 += e0 + e1;
          else if (wi == 1) s1 += e0 + e1;
          else if (wi == 2) s2 += e0 + e1;
          else s3 += e0 + e1;
          asm("v_cvt_pk_bf16_f32 %0, %1, %2"
              : "=v"(pw[kb * 2 + hh][wi]) : "v"(e0), "v"(e1));
        }
    float ssum = (s0 + s1) + (s2 + s3);
    ssum += __shfl_xor(ssum, 32);
    l += ssum;
#pragma unroll
    for (int f = 0; f < 4; f++) {
      asm("v_permlane32_swap_b32 %0, %1" : "+v"(pw[f][0]), "+v"(pw[f][2]));
      asm("v_permlane32_swap_b32 %0, %1" : "+v"(pw[f][1]), "+v"(pw[f][3]));
    }
#pragma unroll
    for (int f = 0; f < 4; f++) {
      u32x4 wv = {pw[f][0], pw[f][1], pw[f][2], pw[f][3]};
      bf16x8 pa = __builtin_bit_cast(bf16x8, wv);
      bf16x8 va = asbf(*(const u16x8*)(Vtile + (2 * f + hi) * 512 + q * 8));
      bf16x8 vb = asbf(*(const u16x8*)(Vtile + (2 * f + hi) * 512 + (32 + q) * 8));
      o0 = mfma32(va, pa, o0);
      o1 = mfma32(vb, pa, o1);
    }
  }
  const float scale = (NS == 1) ? (1.f / l) : 1.f;
#pragma unroll
  for (int r = 0; r < 16; r++) {
    const int dh = (r & 3) + 8 * (r >> 2) + 4 * hi;
    ot[q][dh] = f2bf(o0[r] * scale);
    ot[q][32 + dh] = f2bf(o1[r] * scale);
  }
  asm volatile("s_waitcnt lgkmcnt(0)" ::: "memory");
  __builtin_amdgcn_sched_barrier(0);
  if (NS == 1) {
    u16* op = O + (size_t)(b * Sdim + q0 + q) * Ddim + h * 64 + hi * 32;
#pragma unroll
    for (int j = 0; j < 4; j++)
      *(u16x8*)(op + j * 8) = *(const u16x8*)(&ot[q][hi * 32 + j * 8]);
  } else {
    u16* op = Opart + ((size_t)(z * 32 + bh) * Sdim + q0 + q) * 64 + hi * 32;
#pragma unroll
    for (int j = 0; j < 4; j++)
      *(u16x8*)(op + j * 8) = *(const u16x8*)(&ot[q][hi * 32 + j * 8]);
    if (hi == 0)
      mlp[(size_t)(z * 32 + bh) * Sdim + q0 + q] = make_float2(m, l);
  }
}

// ---------------- combine NS split partials: O = sum(w_z O_z) / sum(w_z l_z) ----------------
template <int NS>
__global__ __launch_bounds__(256) void attn_combine(
    const u16* __restrict__ Opart, const float2* __restrict__ mlp,
    u16* __restrict__ O) {
  const int t = threadIdx.x;
  const int bh = blockIdx.y, b = bh >> 4, h = bh & 15;
  const int q = blockIdx.x * 32 + (t >> 3);
  const int d0 = (t & 7) * 8;
  float2 ml[NS];
  float M = -3.0e38f;
#pragma unroll
  for (int z = 0; z < NS; z++) {
    ml[z] = mlp[(size_t)(z * 32 + bh) * Sdim + q];
    M = fmaxf(M, ml[z].x);
  }
  float acc[8];
#pragma unroll
  for (int i = 0; i < 8; i++) acc[i] = 0.f;
  float wsum = 0.f;
#pragma unroll
  for (int z = 0; z < NS; z++) {
    float w = __expf(ml[z].x - M);
    wsum += w * ml[z].y;
    u16x8 ov = *(const u16x8*)(Opart + ((size_t)(z * 32 + bh) * Sdim + q) * 64 + d0);
#pragma unroll
    for (int i = 0; i < 8; i++) acc[i] += w * bf2f(ov[i]);
  }
  const float inv = 1.f / wsum;
  u16x8 res;
#pragma unroll
  for (int i = 0; i < 8; i++) res[i] = f2bf(acc[i] * inv);
  *(u16x8*)(O + ((size_t)b * Sdim + q) * Ddim + h * 64 + d0) = res;
}

extern "C" void kernel_launch(void* const* d_in, const int* in_sizes, int n_in,
                              void* d_out, int out_size, void* d_ws, size_t ws_size,
                              hipStream_t stream) {
  const float* x = (const float*)d_in[0];
  const float* Wq = (const float*)d_in[1];
  const float* Wk = (const float*)d_in[2];
  const float* Wv = (const float*)d_in[3];
  const float* Wo = (const float*)d_in[4];
  const int* vl = (const int*)d_in[5];
  float* out = (float*)d_out;

  char* ws = (char*)d_ws;
  const size_t SZ_X = (size_t)Bdim * Sdim * Ddim * sizeof(u16);  // 8 MB
  const size_t SZ_W = (size_t)Ddim * Ddim * sizeof(u16);         // 2 MB
  u16* xb = (u16*)ws; ws += SZ_X;
  u16* WqT = (u16*)ws; ws += SZ_W;
  u16* WkT = (u16*)ws; ws += SZ_W;
  u16* WvT = (u16*)ws; ws += SZ_W;
  u16* WoT = (u16*)ws; ws += SZ_W;
  u16* Qb = (u16*)ws; ws += SZ_X;
  u16* Kb = (u16*)ws; ws += SZ_X;
  u16* Vb = (u16*)ws; ws += SZ_X;
  u16* Ob = (u16*)ws; ws += SZ_X;
  u16* Ktb = (u16*)ws; ws += SZ_X;  // fragment-tiled K
  u16* Vtb = (u16*)ws; ws += SZ_X;  // fragment-tiled V^T

  const size_t PER_SPLIT = (size_t)Bdim * Hdim * Sdim * 64 * sizeof(u16) +
                           (size_t)Bdim * Hdim * Sdim * sizeof(float2);
  size_t used = (size_t)(ws - (char*)d_ws);
  size_t avail = (ws_size > used) ? ws_size - used : 0;
  int NS = (avail >= 4 * PER_SPLIT) ? 4 : (avail >= 2 * PER_SPLIT) ? 2 : 1;
  u16* Opart = (u16*)ws;
  float2* mlp = (float2*)(ws + (size_t)NS * Bdim * Hdim * Sdim * 64 * sizeof(u16));

  cvtx<<<dim3((Bdim * Sdim * Ddim) / (8 * 256)), 256, 0, stream>>>(x, xb);
  transw<<<dim3(32, 32, 4), 256, 0, stream>>>(Wq, Wk, Wv, Wo, WqT, WkT, WvT, WoT);
  // QKV as ONE dispatch: grid.y = 24 -> (z = y>>3, n-tile = y&7); 768 blocks = 3/CU.
  gemm128<false><<<dim3(32, 24), 256, 0, stream>>>(xb, WqT, WkT, WvT, Qb, Kb, Vb);
  vtrans<<<dim3(Sdim / 32, Bdim * Hdim), 256, 0, stream>>>(Vb, Vtb);
  tilek<<<dim3((Bdim * Sdim * Ddim / 8) / 256), 256, 0, stream>>>(Kb, Ktb);
  attn_kernel<<<dim3(Sdim / 32, Bdim * Hdim, NS), 64, 0, stream>>>(Qb, Ktb, Vtb, vl, Ob,
                                                                   Opart, mlp);
  if (NS == 4)
    attn_combine<4><<<dim3(Sdim / 32, Bdim * Hdim), 256, 0, stream>>>(Opart, mlp, Ob);
  else if (NS == 2)
    attn_combine<2><<<dim3(Sdim / 32, Bdim * Hdim), 256, 0, stream>>>(Opart, mlp, Ob);
  gemm128<true><<<dim3(32, 8), 256, 0, stream>>>(Ob, WoT, WoT, WoT, out, out, out);
}

// Round 16
// 121.524 us; speedup vs baseline: 1.3237x; 1.0416x over previous
//
#include <hip/hip_runtime.h>

#define Bdim 2
#define Sdim 2048
#define Ddim 1024
#define Hdim 16

typedef unsigned short u16;
typedef u16 u16x8 __attribute__((ext_vector_type(8)));
typedef u16 u16x4 __attribute__((ext_vector_type(4)));
typedef unsigned u32x4 __attribute__((ext_vector_type(4)));
typedef __bf16 bf16x8 __attribute__((ext_vector_type(8)));
typedef float f32x4 __attribute__((ext_vector_type(4)));
typedef float f32x16 __attribute__((ext_vector_type(16)));

static __device__ __forceinline__ u16 f2bf(float f) {
  unsigned u = __float_as_uint(f);
  u += 0x7fffu + ((u >> 16) & 1u);
  return (u16)(u >> 16);
}
static __device__ __forceinline__ float bf2f(u16 v) {
  return __uint_as_float((unsigned)v << 16);
}
static __device__ __forceinline__ bf16x8 asbf(u16x8 v) {
  return __builtin_bit_cast(bf16x8, v);
}
static __device__ __forceinline__ f32x4 mfma16(bf16x8 a, bf16x8 b, f32x4 c) {
  return __builtin_amdgcn_mfma_f32_16x16x32_bf16(a, b, c, 0, 0, 0);
}
static __device__ __forceinline__ f32x16 mfma32(bf16x8 a, bf16x8 b, f32x16 c) {
  return __builtin_amdgcn_mfma_f32_32x32x16_bf16(a, b, c, 0, 0, 0);
}

// Staging-order tile cell for [rows][1024] bf16: 128x64 tiles, cell order inside
// a tile = row*8+ch (the EXACT order gemm128 stages it). Cell unit = 8 u16 (k&7).
// tcell(R,k) = ((R>>7)*16 + (k>>6))*1024 + (R&127)*8 + ((k>>3)&7)
// Gemm staging then reads base + (t+256*i)*16B: fully contiguous 4KB per group
// (the r11 attention TA-fix applied to the GEMM staging path).
static __device__ __forceinline__ size_t tcell(int R, int k) {
  return ((size_t)(R >> 7) * 16 + (k >> 6)) * 1024 + (R & 127) * 8 + ((k >> 3) & 7);
}

// ---------------- cast x (f32 -> bf16) into staging-tiled layout ----------------
__global__ __launch_bounds__(256) void cvtx(const float* __restrict__ x,
                                            u16* __restrict__ xt) {
  int i = blockIdx.x * 256 + threadIdx.x;  // row-major cell id over [4096][1024]
  const float4* xp = (const float4*)x;
  float4 a = xp[2 * i], b = xp[2 * i + 1];
  u16x8 o;
  o[0] = f2bf(a.x); o[1] = f2bf(a.y); o[2] = f2bf(a.z); o[3] = f2bf(a.w);
  o[4] = f2bf(b.x); o[5] = f2bf(b.y); o[6] = f2bf(b.z); o[7] = f2bf(b.w);
  int R = i >> 7, k = (i & 127) * 8;
  ((u16x8*)xt)[tcell(R, k)] = o;
}

// ------ transpose + cast W [K][N] f32 -> staging-tiled WT (rows = N) ------
__global__ __launch_bounds__(256) void transw(
    const float* __restrict__ W0, const float* __restrict__ W1,
    const float* __restrict__ W2, const float* __restrict__ W3,
    u16* __restrict__ T0, u16* __restrict__ T1,
    u16* __restrict__ T2, u16* __restrict__ T3) {
  const float* W = blockIdx.z == 0 ? W0 : blockIdx.z == 1 ? W1 : blockIdx.z == 2 ? W2 : W3;
  u16* T = blockIdx.z == 0 ? T0 : blockIdx.z == 1 ? T1 : blockIdx.z == 2 ? T2 : T3;
  __shared__ float tile[32][33];
  const int t = threadIdx.x;
  const int k0 = blockIdx.x * 32, n0 = blockIdx.y * 32;
  const int r = t >> 3, cq = (t & 7) * 4;
  float4 v = *(const float4*)(W + (size_t)(k0 + r) * Ddim + n0 + cq);
  tile[r][cq] = v.x; tile[r][cq + 1] = v.y; tile[r][cq + 2] = v.z; tile[r][cq + 3] = v.w;
  __syncthreads();
  u16x4 ov;
  ov[0] = f2bf(tile[cq][r]);
  ov[1] = f2bf(tile[cq + 1][r]);
  ov[2] = f2bf(tile[cq + 2][r]);
  ov[3] = f2bf(tile[cq + 3][r]);
  int n = n0 + r, k = k0 + cq;  // k&7 in {0,4}: low/high half of the cell
  *(u16x4*)(T + tcell(n, k) * 8 + (k & 7)) = ov;
}

// -------- transpose V [B,S,D] -> fragment-tiled Vt[bh][kt][c][dh] (attn) --------
__global__ __launch_bounds__(256) void vtrans(const u16* __restrict__ V,
                                              u16* __restrict__ Vt) {
  __shared__ u16 tile[32][72];
  const int t = threadIdx.x;
  const int s0 = blockIdx.x * 32;
  const int bh = blockIdx.y, b = bh >> 4, h = bh & 15;
  {
    int sl = t >> 3, dq = (t & 7) * 8;
    u16x8 v = *(const u16x8*)(V + (size_t)(b * Sdim + s0 + sl) * Ddim + h * 64 + dq);
    *(u16x8*)(&tile[sl][dq]) = v;
  }
  __syncthreads();
  {
    int dl = t >> 2, sq = (t & 3) * 8;
    u16x8 v;
#pragma unroll
    for (int i = 0; i < 8; i++) v[i] = tile[sq + i][dl];
    int s = s0 + sq;
    int kt = s >> 6, c = (s >> 3) & 7;
    *(u16x8*)(Vt + ((((size_t)bh * 32 + kt) * 8 + c) * 64 + dl) * 8) = v;
  }
}

// -------- tile K into fragment-ordered Kt[bh][kt][c][row] (attn) --------
__global__ __launch_bounds__(256) void tilek(const u16* __restrict__ K,
                                             u16* __restrict__ Kt) {
  int tid = blockIdx.x * 256 + threadIdx.x;  // 0 .. 524287
  int row = tid & 63;
  int c = (tid >> 6) & 7;
  int kt = (tid >> 9) & 31;
  int bh = tid >> 14;
  int b = bh >> 4, h = bh & 15;
  u16x8 kc = *(const u16x8*)(K + (size_t)(b * Sdim + kt * 64 + row) * Ddim + h * 64 + c * 8);
  ((u16x8*)Kt)[tid] = kc;
}

// ---------------- 128x128 bf16 MFMA GEMM — staging-tiled operands + T14 prefetch ----------------
// r15 structure unchanged EXCEPT the staging source: A/Bt are pre-tiled so each
// staging load is fully contiguous (cell id = (blk*16+kt)*1024 + t + 256*i).
// r13/r15 profiling showed wall time == per-block critical path dominated by
// scattered 2KB-stride staging (8 lines/instr, ~30 TA-cy); contiguous kills that.
template <bool F32OUT>
__global__ __launch_bounds__(256) void gemm128(
    const u16* __restrict__ A,
    const u16* __restrict__ Bt0, const u16* __restrict__ Bt1, const u16* __restrict__ Bt2,
    void* __restrict__ C0v, void* __restrict__ C1v, void* __restrict__ C2v) {
  __shared__ u16 As[128 * 64];
  __shared__ u16 Bs[128 * 64];
  const int zz = blockIdx.y >> 3;
  const u16* Bt = (zz == 0) ? Bt0 : (zz == 1) ? Bt1 : Bt2;
  void* Cv = (zz == 0) ? C0v : (zz == 1) ? C1v : C2v;

  const int t = threadIdx.x;
  const int lane = t & 63, w = t >> 6;
  const int wm = w >> 1, wn = w & 1;
  const int c = lane & 15, g = lane >> 4;
  const int mb = blockIdx.x, nb = blockIdx.y & 7;
  const float oscale = (!F32OUT && zz == 0) ? 0.125f : 1.0f;

  const f32x4 zv = {0.f, 0.f, 0.f, 0.f};
  f32x4 acc[4][4];
#pragma unroll
  for (int m = 0; m < 4; m++)
#pragma unroll
    for (int n = 0; n < 4; n++) acc[m][n] = zv;

  const u16x8* Ac = (const u16x8*)A;   // cell pointers
  const u16x8* Bc = (const u16x8*)Bt;
  u16x8 ra[4], rb[4];
#pragma unroll
  for (int i = 0; i < 4; i++) {  // prologue: tile kt=0, fully contiguous
    ra[i] = Ac[(size_t)(mb * 16 + 0) * 1024 + t + 256 * i];
    rb[i] = Bc[(size_t)(nb * 16 + 0) * 1024 + t + 256 * i];
  }
#pragma unroll
  for (int i = 0; i < 4; i++) {
    int idx = t + 256 * i;
    int row = idx >> 3, ch = idx & 7;
    int sw = (ch ^ (row & 7)) * 8;
    *(u16x8*)(As + row * 64 + sw) = ra[i];
    *(u16x8*)(Bs + row * 64 + sw) = rb[i];
  }
  __syncthreads();

  for (int kt = 0; kt < 16; ++kt) {
    const bool more = (kt + 1) < 16;
    if (more) {  // issue next-tile loads; latency hides under MFMA phase
#pragma unroll
      for (int i = 0; i < 4; i++) {
        ra[i] = Ac[(size_t)(mb * 16 + kt + 1) * 1024 + t + 256 * i];
        rb[i] = Bc[(size_t)(nb * 16 + kt + 1) * 1024 + t + 256 * i];
      }
    }
#pragma unroll
    for (int kh = 0; kh < 2; kh++) {
      bf16x8 af[4], bfr[4];
#pragma unroll
      for (int m = 0; m < 4; m++) {
        int row = wm * 64 + m * 16 + c;
        int chr = kh * 4 + g;
        af[m] = asbf(*(const u16x8*)(As + row * 64 + ((chr ^ (row & 7)) * 8)));
      }
#pragma unroll
      for (int n = 0; n < 4; n++) {
        int row = wn * 64 + n * 16 + c;
        int chr = kh * 4 + g;
        bfr[n] = asbf(*(const u16x8*)(Bs + row * 64 + ((chr ^ (row & 7)) * 8)));
      }
#pragma unroll
      for (int m = 0; m < 4; m++)
#pragma unroll
        for (int n = 0; n < 4; n++) acc[m][n] = mfma16(af[m], bfr[n], acc[m][n]);
    }
    if (more) {
      __syncthreads();
#pragma unroll
      for (int i = 0; i < 4; i++) {
        int idx = t + 256 * i;
        int row = idx >> 3, ch = idx & 7;
        int sw = (ch ^ (row & 7)) * 8;
        *(u16x8*)(As + row * 64 + sw) = ra[i];
        *(u16x8*)(Bs + row * 64 + sw) = rb[i];
      }
      __syncthreads();
    }
  }
  // epilogue: C/D layout col=lane&15, row=4*(lane>>4)+r  [measured m89/m91]
#pragma unroll
  for (int m = 0; m < 4; m++)
#pragma unroll
    for (int n = 0; n < 4; n++)
#pragma unroll
      for (int r = 0; r < 4; r++) {
        int row = mb * 128 + wm * 64 + m * 16 + 4 * g + r;
        int col = nb * 128 + wn * 64 + n * 16 + c;
        if (F32OUT)
          ((float*)Cv)[(size_t)row * 1024 + col] = acc[m][n][r];
        else
          ((u16*)Cv)[(size_t)row * 1024 + col] = f2bf(acc[m][n][r] * oscale);
      }
}

// ---------------- flash attention: tiled K/V + KV-split (r13-verified body) ----------------
// NS==1 writes O directly in staging-tiled layout (feeds Wo gemm); NS>1 writes
// partials merged by attn_combine (which writes the tiled layout).
__global__ __launch_bounds__(64, 4) void attn_kernel(
    const u16* __restrict__ Q, const u16* __restrict__ Kt,
    const u16* __restrict__ Vt, const int* __restrict__ vlen,
    u16* __restrict__ O, u16* __restrict__ Opart, float2* __restrict__ mlp) {
  __shared__ u16 ot[32][72];
  const int lane = threadIdx.x;
  const int q = lane & 31, hi = lane >> 5;
  const int bh = blockIdx.y, b = bh >> 4, h = bh & 15;
  const int q0 = blockIdx.x * 32;
  const int nv = vlen[b];
  const int NS = gridDim.z, z = blockIdx.z;

  bf16x8 qf[4];
  {
    const u16* qp = Q + (size_t)(b * Sdim + q0 + q) * Ddim + h * 64 + hi * 8;
#pragma unroll
    for (int s = 0; s < 4; s++) qf[s] = asbf(*(const u16x8*)(qp + s * 16));
  }

  f32x16 o0, o1;
#pragma unroll
  for (int r = 0; r < 16; r++) { o0[r] = 0.f; o1[r] = 0.f; }
  float m = -3.0e38f, l = 0.f;

  const int nt = (nv + 63) >> 6;
  const int chunk = (nt + NS - 1) / NS;
  const int t0 = z * chunk;
  const int t1 = min(nt, t0 + chunk);
  for (int kt = t0; kt < t1; ++kt) {
    const int k0 = kt * 64;
    const u16* Ktile = Kt + ((size_t)bh * 32 + kt) * 4096;
    const u16* Vtile = Vt + ((size_t)bh * 32 + kt) * 4096;
    f32x16 sc[2];
#pragma unroll
    for (int kb = 0; kb < 2; kb++) {
      f32x16 acc;
#pragma unroll
      for (int r = 0; r < 16; r++) acc[r] = 0.f;
#pragma unroll
      for (int s = 0; s < 4; s++) {
        bf16x8 kf = asbf(*(const u16x8*)(Ktile + (2 * s + hi) * 512 + (kb * 32 + q) * 8));
        acc = mfma32(kf, qf[s], acc);
      }
      sc[kb] = acc;
    }
    if (k0 + 64 > nv) {
#pragma unroll
      for (int kb = 0; kb < 2; kb++)
#pragma unroll
        for (int r = 0; r < 16; r++) {
          int key = k0 + kb * 32 + (r & 3) + 8 * (r >> 2) + 4 * hi;
          if (key >= nv) sc[kb][r] = -1e30f;
        }
    }
    float mx[16];
#pragma unroll
    for (int r = 0; r < 16; r++) mx[r] = fmaxf(sc[0][r], sc[1][r]);
#pragma unroll
    for (int st = 8; st > 0; st >>= 1)
#pragma unroll
      for (int r = 0; r < st; r++) mx[r] = fmaxf(mx[r], mx[r + st]);
    float tm = fmaxf(mx[0], __shfl_xor(mx[0], 32));
    if (!__all(tm <= m + 8.f)) {
      float mn = fmaxf(m, tm);
      float al = __expf(m - mn);
#pragma unroll
      for (int r = 0; r < 16; r++) { o0[r] *= al; o1[r] *= al; }
      l *= al;
      m = mn;
    }
    unsigned pw[4][4];
    float s0 = 0.f, s1 = 0.f, s2 = 0.f, s3 = 0.f;
#pragma unroll
    for (int kb = 0; kb < 2; kb++)
#pragma unroll
      for (int hh = 0; hh < 2; hh++)
#pragma unroll
        for (int wi = 0; wi < 4; wi++) {
          float e0 = __expf(sc[kb][hh * 8 + wi * 2] - m);
          float e1 = __expf(sc[kb][hh * 8 + wi * 2 + 1] - m);
          if (wi == 0) s0 += e0 + e1;
          else if (wi == 1) s1 += e0 + e1;
          else if (wi == 2) s2 += e0 + e1;
          else s3 += e0 + e1;
          asm("v_cvt_pk_bf16_f32 %0, %1, %2"
              : "=v"(pw[kb * 2 + hh][wi]) : "v"(e0), "v"(e1));
        }
    float ssum = (s0 + s1) + (s2 + s3);
    ssum += __shfl_xor(ssum, 32);
    l += ssum;
#pragma unroll
    for (int f = 0; f < 4; f++) {
      asm("v_permlane32_swap_b32 %0, %1" : "+v"(pw[f][0]), "+v"(pw[f][2]));
      asm("v_permlane32_swap_b32 %0, %1" : "+v"(pw[f][1]), "+v"(pw[f][3]));
    }
#pragma unroll
    for (int f = 0; f < 4; f++) {
      u32x4 wv = {pw[f][0], pw[f][1], pw[f][2], pw[f][3]};
      bf16x8 pa = __builtin_bit_cast(bf16x8, wv);
      bf16x8 va = asbf(*(const u16x8*)(Vtile + (2 * f + hi) * 512 + q * 8));
      bf16x8 vb = asbf(*(const u16x8*)(Vtile + (2 * f + hi) * 512 + (32 + q) * 8));
      o0 = mfma32(va, pa, o0);
      o1 = mfma32(vb, pa, o1);
    }
  }
  const float scale = (NS == 1) ? (1.f / l) : 1.f;
#pragma unroll
  for (int r = 0; r < 16; r++) {
    const int dh = (r & 3) + 8 * (r >> 2) + 4 * hi;
    ot[q][dh] = f2bf(o0[r] * scale);
    ot[q][32 + dh] = f2bf(o1[r] * scale);
  }
  asm volatile("s_waitcnt lgkmcnt(0)" ::: "memory");
  __builtin_amdgcn_sched_barrier(0);
  if (NS == 1) {
    int R = b * Sdim + q0 + q;
    size_t cellbase = ((size_t)(R >> 7) * 16 + h) * 1024 + (R & 127) * 8 + hi * 4;
#pragma unroll
    for (int j = 0; j < 4; j++)
      ((u16x8*)O)[cellbase + j] = *(const u16x8*)(&ot[q][hi * 32 + j * 8]);
  } else {
    u16* op = Opart + ((size_t)(z * 32 + bh) * Sdim + q0 + q) * 64 + hi * 32;
#pragma unroll
    for (int j = 0; j < 4; j++)
      *(u16x8*)(op + j * 8) = *(const u16x8*)(&ot[q][hi * 32 + j * 8]);
    if (hi == 0)
      mlp[(size_t)(z * 32 + bh) * Sdim + q0 + q] = make_float2(m, l);
  }
}

// ---- combine NS split partials -> O in staging-tiled layout (Wo gemm A) ----
template <int NS>
__global__ __launch_bounds__(256) void attn_combine(
    const u16* __restrict__ Opart, const float2* __restrict__ mlp,
    u16* __restrict__ O) {
  const int t = threadIdx.x;
  const int bh = blockIdx.y, b = bh >> 4, h = bh & 15;
  const int q = blockIdx.x * 32 + (t >> 3);
  const int d0 = (t & 7) * 8;
  float2 ml[NS];
  float M = -3.0e38f;
#pragma unroll
  for (int z = 0; z < NS; z++) {
    ml[z] = mlp[(size_t)(z * 32 + bh) * Sdim + q];
    M = fmaxf(M, ml[z].x);
  }
  float acc[8];
#pragma unroll
  for (int i = 0; i < 8; i++) acc[i] = 0.f;
  float wsum = 0.f;
#pragma unroll
  for (int z = 0; z < NS; z++) {
    float w = __expf(ml[z].x - M);
    wsum += w * ml[z].y;
    u16x8 ov = *(const u16x8*)(Opart + ((size_t)(z * 32 + bh) * Sdim + q) * 64 + d0);
#pragma unroll
    for (int i = 0; i < 8; i++) acc[i] += w * bf2f(ov[i]);
  }
  const float inv = 1.f / wsum;
  u16x8 res;
#pragma unroll
  for (int i = 0; i < 8; i++) res[i] = f2bf(acc[i] * inv);
  int R = b * Sdim + q;
  ((u16x8*)O)[((size_t)(R >> 7) * 16 + h) * 1024 + (R & 127) * 8 + (d0 >> 3)] = res;
}

extern "C" void kernel_launch(void* const* d_in, const int* in_sizes, int n_in,
                              void* d_out, int out_size, void* d_ws, size_t ws_size,
                              hipStream_t stream) {
  const float* x = (const float*)d_in[0];
  const float* Wq = (const float*)d_in[1];
  const float* Wk = (const float*)d_in[2];
  const float* Wv = (const float*)d_in[3];
  const float* Wo = (const float*)d_in[4];
  const int* vl = (const int*)d_in[5];
  float* out = (float*)d_out;

  char* ws = (char*)d_ws;
  const size_t SZ_X = (size_t)Bdim * Sdim * Ddim * sizeof(u16);  // 8 MB
  const size_t SZ_W = (size_t)Ddim * Ddim * sizeof(u16);         // 2 MB
  u16* xt = (u16*)ws; ws += SZ_X;   // staging-tiled x
  u16* WqT = (u16*)ws; ws += SZ_W;  // staging-tiled weights
  u16* WkT = (u16*)ws; ws += SZ_W;
  u16* WvT = (u16*)ws; ws += SZ_W;
  u16* WoT = (u16*)ws; ws += SZ_W;
  u16* Qb = (u16*)ws; ws += SZ_X;   // row-major gemm outputs
  u16* Kb = (u16*)ws; ws += SZ_X;
  u16* Vb = (u16*)ws; ws += SZ_X;
  u16* Obt = (u16*)ws; ws += SZ_X;  // staging-tiled attention output
  u16* Ktb = (u16*)ws; ws += SZ_X;  // fragment-tiled K (attn)
  u16* Vtb = (u16*)ws; ws += SZ_X;  // fragment-tiled V^T (attn)

  const size_t PER_SPLIT = (size_t)Bdim * Hdim * Sdim * 64 * sizeof(u16) +
                           (size_t)Bdim * Hdim * Sdim * sizeof(float2);
  size_t used = (size_t)(ws - (char*)d_ws);
  size_t avail = (ws_size > used) ? ws_size - used : 0;
  int NS = (avail >= 4 * PER_SPLIT) ? 4 : (avail >= 2 * PER_SPLIT) ? 2 : 1;
  u16* Opart = (u16*)ws;
  float2* mlp = (float2*)(ws + (size_t)NS * Bdim * Hdim * Sdim * 64 * sizeof(u16));

  cvtx<<<dim3((Bdim * Sdim * Ddim) / (8 * 256)), 256, 0, stream>>>(x, xt);
  transw<<<dim3(32, 32, 4), 256, 0, stream>>>(Wq, Wk, Wv, Wo, WqT, WkT, WvT, WoT);
  // QKV as ONE dispatch: grid.y = 24 -> (z = y>>3, n-tile = y&7); 768 blocks = 3/CU.
  gemm128<false><<<dim3(32, 24), 256, 0, stream>>>(xt, WqT, WkT, WvT, Qb, Kb, Vb);
  vtrans<<<dim3(Sdim / 32, Bdim * Hdim), 256, 0, stream>>>(Vb, Vtb);
  tilek<<<dim3((Bdim * Sdim * Ddim / 8) / 256), 256, 0, stream>>>(Kb, Ktb);
  attn_kernel<<<dim3(Sdim / 32, Bdim * Hdim, NS), 64, 0, stream>>>(Qb, Ktb, Vtb, vl, Obt,
                                                                   Opart, mlp);
  if (NS == 4)
    attn_combine<4><<<dim3(Sdim / 32, Bdim * Hdim), 256, 0, stream>>>(Opart, mlp, Obt);
  else if (NS == 2)
    attn_combine<2><<<dim3(Sdim / 32, Bdim * Hdim), 256, 0, stream>>>(Opart, mlp, Obt);
  gemm128<true><<<dim3(32, 8), 256, 0, stream>>>(Obt, WoT, WoT, WoT, out, out, out);
}

// Round 17
// 119.304 us; speedup vs baseline: 1.3483x; 1.0186x over previous
//
#include <hip/hip_runtime.h>

#define Bdim 2
#define Sdim 2048
#define Ddim 1024
#define Hdim 16

typedef unsigned short u16;
typedef u16 u16x8 __attribute__((ext_vector_type(8)));
typedef u16 u16x4 __attribute__((ext_vector_type(4)));
typedef unsigned u32x4 __attribute__((ext_vector_type(4)));
typedef __bf16 bf16x8 __attribute__((ext_vector_type(8)));
typedef float f32x4 __attribute__((ext_vector_type(4)));
typedef float f32x16 __attribute__((ext_vector_type(16)));

static __device__ __forceinline__ u16 f2bf(float f) {
  unsigned u = __float_as_uint(f);
  u += 0x7fffu + ((u >> 16) & 1u);
  return (u16)(u >> 16);
}
static __device__ __forceinline__ float bf2f(u16 v) {
  return __uint_as_float((unsigned)v << 16);
}
static __device__ __forceinline__ bf16x8 asbf(u16x8 v) {
  return __builtin_bit_cast(bf16x8, v);
}
static __device__ __forceinline__ f32x4 mfma16(bf16x8 a, bf16x8 b, f32x4 c) {
  return __builtin_amdgcn_mfma_f32_16x16x32_bf16(a, b, c, 0, 0, 0);
}
static __device__ __forceinline__ f32x16 mfma32(bf16x8 a, bf16x8 b, f32x16 c) {
  return __builtin_amdgcn_mfma_f32_32x32x16_bf16(a, b, c, 0, 0, 0);
}

// Staging-order tile cell for [rows][1024] bf16: 128x64 tiles, cell order inside
// a tile = row*8+ch (the EXACT order gemm128 stages it). Cell unit = 8 u16 (k&7).
// tcell(R,k) = ((R>>7)*16 + (k>>6))*1024 + (R&127)*8 + ((k>>3)&7)
static __device__ __forceinline__ size_t tcell(int R, int k) {
  return ((size_t)(R >> 7) * 16 + (k >> 6)) * 1024 + (R & 127) * 8 + ((k >> 3) & 7);
}

// ---------------- cast x (f32 -> bf16) into staging-tiled layout ----------------
__global__ __launch_bounds__(256) void cvtx(const float* __restrict__ x,
                                            u16* __restrict__ xt) {
  int i = blockIdx.x * 256 + threadIdx.x;  // row-major cell id over [4096][1024]
  const float4* xp = (const float4*)x;
  float4 a = xp[2 * i], b = xp[2 * i + 1];
  u16x8 o;
  o[0] = f2bf(a.x); o[1] = f2bf(a.y); o[2] = f2bf(a.z); o[3] = f2bf(a.w);
  o[4] = f2bf(b.x); o[5] = f2bf(b.y); o[6] = f2bf(b.z); o[7] = f2bf(b.w);
  int R = i >> 7, k = (i & 127) * 8;
  ((u16x8*)xt)[tcell(R, k)] = o;
}

// ------ transpose + cast W [K][N] f32 -> staging-tiled WT (rows = N) ------
__global__ __launch_bounds__(256) void transw(
    const float* __restrict__ W0, const float* __restrict__ W1,
    const float* __restrict__ W2, const float* __restrict__ W3,
    u16* __restrict__ T0, u16* __restrict__ T1,
    u16* __restrict__ T2, u16* __restrict__ T3) {
  const float* W = blockIdx.z == 0 ? W0 : blockIdx.z == 1 ? W1 : blockIdx.z == 2 ? W2 : W3;
  u16* T = blockIdx.z == 0 ? T0 : blockIdx.z == 1 ? T1 : blockIdx.z == 2 ? T2 : T3;
  __shared__ float tile[32][33];
  const int t = threadIdx.x;
  const int k0 = blockIdx.x * 32, n0 = blockIdx.y * 32;
  const int r = t >> 3, cq = (t & 7) * 4;
  float4 v = *(const float4*)(W + (size_t)(k0 + r) * Ddim + n0 + cq);
  tile[r][cq] = v.x; tile[r][cq + 1] = v.y; tile[r][cq + 2] = v.z; tile[r][cq + 3] = v.w;
  __syncthreads();
  u16x4 ov;
  ov[0] = f2bf(tile[cq][r]);
  ov[1] = f2bf(tile[cq + 1][r]);
  ov[2] = f2bf(tile[cq + 2][r]);
  ov[3] = f2bf(tile[cq + 3][r]);
  int n = n0 + r, k = k0 + cq;  // k&7 in {0,4}: low/high half of the cell
  *(u16x4*)(T + tcell(n, k) * 8 + (k & 7)) = ov;
}

// -------- transpose V [B,S,D] -> fragment-tiled Vt[bh][kt][c][dh] (attn) --------
__global__ __launch_bounds__(256) void vtrans(const u16* __restrict__ V,
                                              u16* __restrict__ Vt) {
  __shared__ u16 tile[32][72];
  const int t = threadIdx.x;
  const int s0 = blockIdx.x * 32;
  const int bh = blockIdx.y, b = bh >> 4, h = bh & 15;
  {
    int sl = t >> 3, dq = (t & 7) * 8;
    u16x8 v = *(const u16x8*)(V + (size_t)(b * Sdim + s0 + sl) * Ddim + h * 64 + dq);
    *(u16x8*)(&tile[sl][dq]) = v;
  }
  __syncthreads();
  {
    int dl = t >> 2, sq = (t & 3) * 8;
    u16x8 v;
#pragma unroll
    for (int i = 0; i < 8; i++) v[i] = tile[sq + i][dl];
    int s = s0 + sq;
    int kt = s >> 6, c = (s >> 3) & 7;
    *(u16x8*)(Vt + ((((size_t)bh * 32 + kt) * 8 + c) * 64 + dl) * 8) = v;
  }
}

// -------- tile K into fragment-ordered Kt[bh][kt][c][row] (attn) --------
__global__ __launch_bounds__(256) void tilek(const u16* __restrict__ K,
                                             u16* __restrict__ Kt) {
  int tid = blockIdx.x * 256 + threadIdx.x;  // 0 .. 524287
  int row = tid & 63;
  int c = (tid >> 6) & 7;
  int kt = (tid >> 9) & 31;
  int bh = tid >> 14;
  int b = bh >> 4, h = bh & 15;
  u16x8 kc = *(const u16x8*)(K + (size_t)(b * Sdim + kt * 64 + row) * Ddim + h * 64 + c * 8);
  ((u16x8*)Kt)[tid] = kc;
}

// ---------------- 128x128 bf16 MFMA GEMM — staging-tiled operands + T14 prefetch ----------------
// (r16-verified: QKV dropped below 39us with contiguous staging loads.)
template <bool F32OUT>
__global__ __launch_bounds__(256) void gemm128(
    const u16* __restrict__ A,
    const u16* __restrict__ Bt0, const u16* __restrict__ Bt1, const u16* __restrict__ Bt2,
    void* __restrict__ C0v, void* __restrict__ C1v, void* __restrict__ C2v) {
  __shared__ u16 As[128 * 64];
  __shared__ u16 Bs[128 * 64];
  const int zz = blockIdx.y >> 3;
  const u16* Bt = (zz == 0) ? Bt0 : (zz == 1) ? Bt1 : Bt2;
  void* Cv = (zz == 0) ? C0v : (zz == 1) ? C1v : C2v;

  const int t = threadIdx.x;
  const int lane = t & 63, w = t >> 6;
  const int wm = w >> 1, wn = w & 1;
  const int c = lane & 15, g = lane >> 4;
  const int mb = blockIdx.x, nb = blockIdx.y & 7;
  const float oscale = (!F32OUT && zz == 0) ? 0.125f : 1.0f;

  const f32x4 zv = {0.f, 0.f, 0.f, 0.f};
  f32x4 acc[4][4];
#pragma unroll
  for (int m = 0; m < 4; m++)
#pragma unroll
    for (int n = 0; n < 4; n++) acc[m][n] = zv;

  const u16x8* Ac = (const u16x8*)A;
  const u16x8* Bc = (const u16x8*)Bt;
  u16x8 ra[4], rb[4];
#pragma unroll
  for (int i = 0; i < 4; i++) {
    ra[i] = Ac[(size_t)(mb * 16 + 0) * 1024 + t + 256 * i];
    rb[i] = Bc[(size_t)(nb * 16 + 0) * 1024 + t + 256 * i];
  }
#pragma unroll
  for (int i = 0; i < 4; i++) {
    int idx = t + 256 * i;
    int row = idx >> 3, ch = idx & 7;
    int sw = (ch ^ (row & 7)) * 8;
    *(u16x8*)(As + row * 64 + sw) = ra[i];
    *(u16x8*)(Bs + row * 64 + sw) = rb[i];
  }
  __syncthreads();

  for (int kt = 0; kt < 16; ++kt) {
    const bool more = (kt + 1) < 16;
    if (more) {
#pragma unroll
      for (int i = 0; i < 4; i++) {
        ra[i] = Ac[(size_t)(mb * 16 + kt + 1) * 1024 + t + 256 * i];
        rb[i] = Bc[(size_t)(nb * 16 + kt + 1) * 1024 + t + 256 * i];
      }
    }
#pragma unroll
    for (int kh = 0; kh < 2; kh++) {
      bf16x8 af[4], bfr[4];
#pragma unroll
      for (int m = 0; m < 4; m++) {
        int row = wm * 64 + m * 16 + c;
        int chr = kh * 4 + g;
        af[m] = asbf(*(const u16x8*)(As + row * 64 + ((chr ^ (row & 7)) * 8)));
      }
#pragma unroll
      for (int n = 0; n < 4; n++) {
        int row = wn * 64 + n * 16 + c;
        int chr = kh * 4 + g;
        bfr[n] = asbf(*(const u16x8*)(Bs + row * 64 + ((chr ^ (row & 7)) * 8)));
      }
#pragma unroll
      for (int m = 0; m < 4; m++)
#pragma unroll
        for (int n = 0; n < 4; n++) acc[m][n] = mfma16(af[m], bfr[n], acc[m][n]);
    }
    if (more) {
      __syncthreads();
#pragma unroll
      for (int i = 0; i < 4; i++) {
        int idx = t + 256 * i;
        int row = idx >> 3, ch = idx & 7;
        int sw = (ch ^ (row & 7)) * 8;
        *(u16x8*)(As + row * 64 + sw) = ra[i];
        *(u16x8*)(Bs + row * 64 + sw) = rb[i];
      }
      __syncthreads();
    }
  }
  // epilogue: C/D layout col=lane&15, row=4*(lane>>4)+r  [measured m89/m91]
#pragma unroll
  for (int m = 0; m < 4; m++)
#pragma unroll
    for (int n = 0; n < 4; n++)
#pragma unroll
      for (int r = 0; r < 4; r++) {
        int row = mb * 128 + wm * 64 + m * 16 + 4 * g + r;
        int col = nb * 128 + wn * 64 + n * 16 + c;
        if (F32OUT)
          ((float*)Cv)[(size_t)row * 1024 + col] = acc[m][n][r];
        else
          ((u16*)Cv)[(size_t)row * 1024 + col] = f2bf(acc[m][n][r] * oscale);
      }
}

// ---------------- 64x128-tile GEMM for the Wo projection (f32 out) ----------------
// r16 arithmetic: Wo at 256 blocks = 1 block/CU ran ~same wall time as QKV with
// 1/3 the FLOPs (wall time == per-block path). 64-row tiles -> 512 blocks = 2/CU
// doubles co-residency and halves per-block work. Waves 2x2, each 32x64 (acc[2][4]).
// A 64-row tile = contiguous 512-cell half of a 128-row tcell block.
__global__ __launch_bounds__(256) void gemm_wo(
    const u16* __restrict__ A, const u16* __restrict__ Bt, float* __restrict__ C) {
  __shared__ u16 As[64 * 64];
  __shared__ u16 Bs[128 * 64];
  const int t = threadIdx.x;
  const int lane = t & 63, w = t >> 6;
  const int wm = w >> 1, wn = w & 1;
  const int c = lane & 15, g = lane >> 4;
  const int mb = blockIdx.x, nb = blockIdx.y;  // 64 m-tiles, 8 n-tiles

  const f32x4 zv = {0.f, 0.f, 0.f, 0.f};
  f32x4 acc[2][4];
#pragma unroll
  for (int m = 0; m < 2; m++)
#pragma unroll
    for (int n = 0; n < 4; n++) acc[m][n] = zv;

  const u16x8* Ac = (const u16x8*)A;
  const u16x8* Bc = (const u16x8*)Bt;
  const size_t abase = (size_t)(mb >> 1) * 16384 + (size_t)(mb & 1) * 512;  // cells
  u16x8 ra[2], rb[4];
#pragma unroll
  for (int i = 0; i < 2; i++) ra[i] = Ac[abase + 0 * 1024 + t + 256 * i];
#pragma unroll
  for (int i = 0; i < 4; i++) rb[i] = Bc[(size_t)(nb * 16 + 0) * 1024 + t + 256 * i];
  {
#pragma unroll
    for (int i = 0; i < 2; i++) {
      int idx = t + 256 * i;
      int row = idx >> 3, ch = idx & 7;
      *(u16x8*)(As + row * 64 + ((ch ^ (row & 7)) * 8)) = ra[i];
    }
#pragma unroll
    for (int i = 0; i < 4; i++) {
      int idx = t + 256 * i;
      int row = idx >> 3, ch = idx & 7;
      *(u16x8*)(Bs + row * 64 + ((ch ^ (row & 7)) * 8)) = rb[i];
    }
  }
  __syncthreads();

  for (int kt = 0; kt < 16; ++kt) {
    const bool more = (kt + 1) < 16;
    if (more) {
#pragma unroll
      for (int i = 0; i < 2; i++) ra[i] = Ac[abase + (size_t)(kt + 1) * 1024 + t + 256 * i];
#pragma unroll
      for (int i = 0; i < 4; i++)
        rb[i] = Bc[(size_t)(nb * 16 + kt + 1) * 1024 + t + 256 * i];
    }
#pragma unroll
    for (int kh = 0; kh < 2; kh++) {
      bf16x8 af[2], bfr[4];
#pragma unroll
      for (int m = 0; m < 2; m++) {
        int row = wm * 32 + m * 16 + c;
        int chr = kh * 4 + g;
        af[m] = asbf(*(const u16x8*)(As + row * 64 + ((chr ^ (row & 7)) * 8)));
      }
#pragma unroll
      for (int n = 0; n < 4; n++) {
        int row = wn * 64 + n * 16 + c;
        int chr = kh * 4 + g;
        bfr[n] = asbf(*(const u16x8*)(Bs + row * 64 + ((chr ^ (row & 7)) * 8)));
      }
#pragma unroll
      for (int m = 0; m < 2; m++)
#pragma unroll
        for (int n = 0; n < 4; n++) acc[m][n] = mfma16(af[m], bfr[n], acc[m][n]);
    }
    if (more) {
      __syncthreads();
#pragma unroll
      for (int i = 0; i < 2; i++) {
        int idx = t + 256 * i;
        int row = idx >> 3, ch = idx & 7;
        *(u16x8*)(As + row * 64 + ((ch ^ (row & 7)) * 8)) = ra[i];
      }
#pragma unroll
      for (int i = 0; i < 4; i++) {
        int idx = t + 256 * i;
        int row = idx >> 3, ch = idx & 7;
        *(u16x8*)(Bs + row * 64 + ((ch ^ (row & 7)) * 8)) = rb[i];
      }
      __syncthreads();
    }
  }
#pragma unroll
  for (int m = 0; m < 2; m++)
#pragma unroll
    for (int n = 0; n < 4; n++)
#pragma unroll
      for (int r = 0; r < 4; r++) {
        int row = mb * 64 + wm * 32 + m * 16 + 4 * g + r;
        int col = nb * 128 + wn * 64 + n * 16 + c;
        C[(size_t)row * 1024 + col] = acc[m][n][r];
      }
}

// ---------------- flash attention: tiled K/V + KV-split (r13-verified body) ----------------
__global__ __launch_bounds__(64, 4) void attn_kernel(
    const u16* __restrict__ Q, const u16* __restrict__ Kt,
    const u16* __restrict__ Vt, const int* __restrict__ vlen,
    u16* __restrict__ O, u16* __restrict__ Opart, float2* __restrict__ mlp) {
  __shared__ u16 ot[32][72];
  const int lane = threadIdx.x;
  const int q = lane & 31, hi = lane >> 5;
  const int bh = blockIdx.y, b = bh >> 4, h = bh & 15;
  const int q0 = blockIdx.x * 32;
  const int nv = vlen[b];
  const int NS = gridDim.z, z = blockIdx.z;

  bf16x8 qf[4];
  {
    const u16* qp = Q + (size_t)(b * Sdim + q0 + q) * Ddim + h * 64 + hi * 8;
#pragma unroll
    for (int s = 0; s < 4; s++) qf[s] = asbf(*(const u16x8*)(qp + s * 16));
  }

  f32x16 o0, o1;
#pragma unroll
  for (int r = 0; r < 16; r++) { o0[r] = 0.f; o1[r] = 0.f; }
  float m = -3.0e38f, l = 0.f;

  const int nt = (nv + 63) >> 6;
  const int chunk = (nt + NS - 1) / NS;
  const int t0 = z * chunk;
  const int t1 = min(nt, t0 + chunk);
  for (int kt = t0; kt < t1; ++kt) {
    const int k0 = kt * 64;
    const u16* Ktile = Kt + ((size_t)bh * 32 + kt) * 4096;
    const u16* Vtile = Vt + ((size_t)bh * 32 + kt) * 4096;
    f32x16 sc[2];
#pragma unroll
    for (int kb = 0; kb < 2; kb++) {
      f32x16 acc;
#pragma unroll
      for (int r = 0; r < 16; r++) acc[r] = 0.f;
#pragma unroll
      for (int s = 0; s < 4; s++) {
        bf16x8 kf = asbf(*(const u16x8*)(Ktile + (2 * s + hi) * 512 + (kb * 32 + q) * 8));
        acc = mfma32(kf, qf[s], acc);
      }
      sc[kb] = acc;
    }
    if (k0 + 64 > nv) {
#pragma unroll
      for (int kb = 0; kb < 2; kb++)
#pragma unroll
        for (int r = 0; r < 16; r++) {
          int key = k0 + kb * 32 + (r & 3) + 8 * (r >> 2) + 4 * hi;
          if (key >= nv) sc[kb][r] = -1e30f;
        }
    }
    float mx[16];
#pragma unroll
    for (int r = 0; r < 16; r++) mx[r] = fmaxf(sc[0][r], sc[1][r]);
#pragma unroll
    for (int st = 8; st > 0; st >>= 1)
#pragma unroll
      for (int r = 0; r < st; r++) mx[r] = fmaxf(mx[r], mx[r + st]);
    float tm = fmaxf(mx[0], __shfl_xor(mx[0], 32));
    if (!__all(tm <= m + 8.f)) {
      float mn = fmaxf(m, tm);
      float al = __expf(m - mn);
#pragma unroll
      for (int r = 0; r < 16; r++) { o0[r] *= al; o1[r] *= al; }
      l *= al;
      m = mn;
    }
    unsigned pw[4][4];
    float s0 = 0.f, s1 = 0.f, s2 = 0.f, s3 = 0.f;
#pragma unroll
    for (int kb = 0; kb < 2; kb++)
#pragma unroll
      for (int hh = 0; hh < 2; hh++)
#pragma unroll
        for (int wi = 0; wi < 4; wi++) {
          float e0 = __expf(sc[kb][hh * 8 + wi * 2] - m);
          float e1 = __expf(sc[kb][hh * 8 + wi * 2 + 1] - m);
          if (wi == 0) s0 += e0 + e1;
          else if (wi == 1) s1 += e0 + e1;
          else if (wi == 2) s2 += e0 + e1;
          else s3 += e0 + e1;
          asm("v_cvt_pk_bf16_f32 %0, %1, %2"
              : "=v"(pw[kb * 2 + hh][wi]) : "v"(e0), "v"(e1));
        }
    float ssum = (s0 + s1) + (s2 + s3);
    ssum += __shfl_xor(ssum, 32);
    l += ssum;
#pragma unroll
    for (int f = 0; f < 4; f++) {
      asm("v_permlane32_swap_b32 %0, %1" : "+v"(pw[f][0]), "+v"(pw[f][2]));
      asm("v_permlane32_swap_b32 %0, %1" : "+v"(pw[f][1]), "+v"(pw[f][3]));
    }
#pragma unroll
    for (int f = 0; f < 4; f++) {
      u32x4 wv = {pw[f][0], pw[f][1], pw[f][2], pw[f][3]};
      bf16x8 pa = __builtin_bit_cast(bf16x8, wv);
      bf16x8 va = asbf(*(const u16x8*)(Vtile + (2 * f + hi) * 512 + q * 8));
      bf16x8 vb = asbf(*(const u16x8*)(Vtile + (2 * f + hi) * 512 + (32 + q) * 8));
      o0 = mfma32(va, pa, o0);
      o1 = mfma32(vb, pa, o1);
    }
  }
  const float scale = (NS == 1) ? (1.f / l) : 1.f;
#pragma unroll
  for (int r = 0; r < 16; r++) {
    const int dh = (r & 3) + 8 * (r >> 2) + 4 * hi;
    ot[q][dh] = f2bf(o0[r] * scale);
    ot[q][32 + dh] = f2bf(o1[r] * scale);
  }
  asm volatile("s_waitcnt lgkmcnt(0)" ::: "memory");
  __builtin_amdgcn_sched_barrier(0);
  if (NS == 1) {
    int R = b * Sdim + q0 + q;
    size_t cellbase = ((size_t)(R >> 7) * 16 + h) * 1024 + (R & 127) * 8 + hi * 4;
#pragma unroll
    for (int j = 0; j < 4; j++)
      ((u16x8*)O)[cellbase + j] = *(const u16x8*)(&ot[q][hi * 32 + j * 8]);
  } else {
    u16* op = Opart + ((size_t)(z * 32 + bh) * Sdim + q0 + q) * 64 + hi * 32;
#pragma unroll
    for (int j = 0; j < 4; j++)
      *(u16x8*)(op + j * 8) = *(const u16x8*)(&ot[q][hi * 32 + j * 8]);
    if (hi == 0)
      mlp[(size_t)(z * 32 + bh) * Sdim + q0 + q] = make_float2(m, l);
  }
}

// ---- combine NS split partials -> O in staging-tiled layout (Wo gemm A) ----
template <int NS>
__global__ __launch_bounds__(256) void attn_combine(
    const u16* __restrict__ Opart, const float2* __restrict__ mlp,
    u16* __restrict__ O) {
  const int t = threadIdx.x;
  const int bh = blockIdx.y, b = bh >> 4, h = bh & 15;
  const int q = blockIdx.x * 32 + (t >> 3);
  const int d0 = (t & 7) * 8;
  float2 ml[NS];
  float M = -3.0e38f;
#pragma unroll
  for (int z = 0; z < NS; z++) {
    ml[z] = mlp[(size_t)(z * 32 + bh) * Sdim + q];
    M = fmaxf(M, ml[z].x);
  }
  float acc[8];
#pragma unroll
  for (int i = 0; i < 8; i++) acc[i] = 0.f;
  float wsum = 0.f;
#pragma unroll
  for (int z = 0; z < NS; z++) {
    float w = __expf(ml[z].x - M);
    wsum += w * ml[z].y;
    u16x8 ov = *(const u16x8*)(Opart + ((size_t)(z * 32 + bh) * Sdim + q) * 64 + d0);
#pragma unroll
    for (int i = 0; i < 8; i++) acc[i] += w * bf2f(ov[i]);
  }
  const float inv = 1.f / wsum;
  u16x8 res;
#pragma unroll
  for (int i = 0; i < 8; i++) res[i] = f2bf(acc[i] * inv);
  int R = b * Sdim + q;
  ((u16x8*)O)[((size_t)(R >> 7) * 16 + h) * 1024 + (R & 127) * 8 + (d0 >> 3)] = res;
}

extern "C" void kernel_launch(void* const* d_in, const int* in_sizes, int n_in,
                              void* d_out, int out_size, void* d_ws, size_t ws_size,
                              hipStream_t stream) {
  const float* x = (const float*)d_in[0];
  const float* Wq = (const float*)d_in[1];
  const float* Wk = (const float*)d_in[2];
  const float* Wv = (const float*)d_in[3];
  const float* Wo = (const float*)d_in[4];
  const int* vl = (const int*)d_in[5];
  float* out = (float*)d_out;

  char* ws = (char*)d_ws;
  const size_t SZ_X = (size_t)Bdim * Sdim * Ddim * sizeof(u16);  // 8 MB
  const size_t SZ_W = (size_t)Ddim * Ddim * sizeof(u16);         // 2 MB
  u16* xt = (u16*)ws; ws += SZ_X;   // staging-tiled x
  u16* WqT = (u16*)ws; ws += SZ_W;  // staging-tiled weights
  u16* WkT = (u16*)ws; ws += SZ_W;
  u16* WvT = (u16*)ws; ws += SZ_W;
  u16* WoT = (u16*)ws; ws += SZ_W;
  u16* Qb = (u16*)ws; ws += SZ_X;   // row-major gemm outputs
  u16* Kb = (u16*)ws; ws += SZ_X;
  u16* Vb = (u16*)ws; ws += SZ_X;
  u16* Obt = (u16*)ws; ws += SZ_X;  // staging-tiled attention output
  u16* Ktb = (u16*)ws; ws += SZ_X;  // fragment-tiled K (attn)
  u16* Vtb = (u16*)ws; ws += SZ_X;  // fragment-tiled V^T (attn)

  const size_t PER_SPLIT = (size_t)Bdim * Hdim * Sdim * 64 * sizeof(u16) +
                           (size_t)Bdim * Hdim * Sdim * sizeof(float2);
  size_t used = (size_t)(ws - (char*)d_ws);
  size_t avail = (ws_size > used) ? ws_size - used : 0;
  int NS = (avail >= 4 * PER_SPLIT) ? 4 : (avail >= 2 * PER_SPLIT) ? 2 : 1;
  u16* Opart = (u16*)ws;
  float2* mlp = (float2*)(ws + (size_t)NS * Bdim * Hdim * Sdim * 64 * sizeof(u16));

  cvtx<<<dim3((Bdim * Sdim * Ddim) / (8 * 256)), 256, 0, stream>>>(x, xt);
  transw<<<dim3(32, 32, 4), 256, 0, stream>>>(Wq, Wk, Wv, Wo, WqT, WkT, WvT, WoT);
  // QKV as ONE dispatch: grid.y = 24 -> (z = y>>3, n-tile = y&7); 768 blocks = 3/CU.
  gemm128<false><<<dim3(32, 24), 256, 0, stream>>>(xt, WqT, WkT, WvT, Qb, Kb, Vb);
  vtrans<<<dim3(Sdim / 32, Bdim * Hdim), 256, 0, stream>>>(Vb, Vtb);
  tilek<<<dim3((Bdim * Sdim * Ddim / 8) / 256), 256, 0, stream>>>(Kb, Ktb);
  attn_kernel<<<dim3(Sdim / 32, Bdim * Hdim, NS), 64, 0, stream>>>(Qb, Ktb, Vtb, vl, Obt,
                                                                   Opart, mlp);
  if (NS == 4)
    attn_combine<4><<<dim3(Sdim / 32, Bdim * Hdim), 256, 0, stream>>>(Opart, mlp, Obt);
  else if (NS == 2)
    attn_combine<2><<<dim3(Sdim / 32, Bdim * Hdim), 256, 0, stream>>>(Opart, mlp, Obt);
  // Wo: 64x128 tiles -> 512 blocks = 2/CU (r16: 1/CU left it at ~245 TF).
  gemm_wo<<<dim3(64, 8), 256, 0, stream>>>(Obt, WoT, out);
}

// Round 20
// 109.320 us; speedup vs baseline: 1.4715x; 1.0913x over previous
//
#include <hip/hip_runtime.h>

#define Bdim 2
#define Sdim 2048
#define Ddim 1024
#define Hdim 16

typedef unsigned short u16;
typedef u16 u16x8 __attribute__((ext_vector_type(8)));
typedef u16 u16x4 __attribute__((ext_vector_type(4)));
typedef unsigned u32x4 __attribute__((ext_vector_type(4)));
typedef __bf16 bf16x8 __attribute__((ext_vector_type(8)));
typedef float f32x4 __attribute__((ext_vector_type(4)));
typedef float f32x16 __attribute__((ext_vector_type(16)));

static __device__ __forceinline__ u16 f2bf(float f) {
  unsigned u = __float_as_uint(f);
  u += 0x7fffu + ((u >> 16) & 1u);
  return (u16)(u >> 16);
}
static __device__ __forceinline__ float bf2f(u16 v) {
  return __uint_as_float((unsigned)v << 16);
}
static __device__ __forceinline__ bf16x8 asbf(u16x8 v) {
  return __builtin_bit_cast(bf16x8, v);
}
static __device__ __forceinline__ f32x4 mfma16(bf16x8 a, bf16x8 b, f32x4 c) {
  return __builtin_amdgcn_mfma_f32_16x16x32_bf16(a, b, c, 0, 0, 0);
}
static __device__ __forceinline__ f32x16 mfma32(bf16x8 a, bf16x8 b, f32x16 c) {
  return __builtin_amdgcn_mfma_f32_32x32x16_bf16(a, b, c, 0, 0, 0);
}

// Staging-order tile cell for [rows][1024] bf16 (gemm operand layout, r16-verified):
// tcell(R,k) = ((R>>7)*16 + (k>>6))*1024 + (R&127)*8 + ((k>>3)&7), cell = 8 u16.
static __device__ __forceinline__ size_t tcell(int R, int k) {
  return ((size_t)(R >> 7) * 16 + (k >> 6)) * 1024 + (R & 127) * 8 + ((k >> 3) & 7);
}

// ---------------- cast x (f32 -> bf16) into staging-tiled layout ----------------
__global__ __launch_bounds__(256) void cvtx(const float* __restrict__ x,
                                            u16* __restrict__ xt) {
  int i = blockIdx.x * 256 + threadIdx.x;  // row-major cell id over [4096][1024]
  const float4* xp = (const float4*)x;
  float4 a = xp[2 * i], b = xp[2 * i + 1];
  u16x8 o;
  o[0] = f2bf(a.x); o[1] = f2bf(a.y); o[2] = f2bf(a.z); o[3] = f2bf(a.w);
  o[4] = f2bf(b.x); o[5] = f2bf(b.y); o[6] = f2bf(b.z); o[7] = f2bf(b.w);
  int R = i >> 7, k = (i & 127) * 8;
  ((u16x8*)xt)[tcell(R, k)] = o;
}

// ------ transpose + cast W [K][N] f32 -> staging-tiled WT (rows = N) ------
__global__ __launch_bounds__(256) void transw(
    const float* __restrict__ W0, const float* __restrict__ W1,
    const float* __restrict__ W2, const float* __restrict__ W3,
    u16* __restrict__ T0, u16* __restrict__ T1,
    u16* __restrict__ T2, u16* __restrict__ T3) {
  const float* W = blockIdx.z == 0 ? W0 : blockIdx.z == 1 ? W1 : blockIdx.z == 2 ? W2 : W3;
  u16* T = blockIdx.z == 0 ? T0 : blockIdx.z == 1 ? T1 : blockIdx.z == 2 ? T2 : T3;
  __shared__ float tile[32][33];
  const int t = threadIdx.x;
  const int k0 = blockIdx.x * 32, n0 = blockIdx.y * 32;
  const int r = t >> 3, cq = (t & 7) * 4;
  float4 v = *(const float4*)(W + (size_t)(k0 + r) * Ddim + n0 + cq);
  tile[r][cq] = v.x; tile[r][cq + 1] = v.y; tile[r][cq + 2] = v.z; tile[r][cq + 3] = v.w;
  __syncthreads();
  u16x4 ov;
  ov[0] = f2bf(tile[cq][r]);
  ov[1] = f2bf(tile[cq + 1][r]);
  ov[2] = f2bf(tile[cq + 2][r]);
  ov[3] = f2bf(tile[cq + 3][r]);
  int n = n0 + r, k = k0 + cq;
  *(u16x4*)(T + tcell(n, k) * 8 + (k & 7)) = ov;
}

// ---------------- QKV GEMM: staging-tiled operands, ATTN-TILED outputs ----------------
// Epilogue writes Q,K in Kt layout [bh][kt][dhchunk][row] and V in Vt layout
// [bh][kt][seqchunk][dh] directly -> tilek & vtrans kernels deleted (r17 budget:
// ~11us of pure permutation + 64MB traffic). V's 4 acc rows = 4 consecutive u16
// -> one 8B store per (m,n). Q scaled by 0.125 here.
__global__ __launch_bounds__(256) void gemm_qkv(
    const u16* __restrict__ A,
    const u16* __restrict__ Bt0, const u16* __restrict__ Bt1, const u16* __restrict__ Bt2,
    u16* __restrict__ Qt, u16* __restrict__ Kt, u16* __restrict__ Vt) {
  __shared__ u16 As[128 * 64];
  __shared__ u16 Bs[128 * 64];
  const int zz = blockIdx.y >> 3;
  const u16* Bt = (zz == 0) ? Bt0 : (zz == 1) ? Bt1 : Bt2;

  const int t = threadIdx.x;
  const int lane = t & 63, w = t >> 6;
  const int wm = w >> 1, wn = w & 1;
  const int c = lane & 15, g = lane >> 4;
  const int mb = blockIdx.x, nb = blockIdx.y & 7;
  const float oscale = (zz == 0) ? 0.125f : 1.0f;

  const f32x4 zv = {0.f, 0.f, 0.f, 0.f};
  f32x4 acc[4][4];
#pragma unroll
  for (int m = 0; m < 4; m++)
#pragma unroll
    for (int n = 0; n < 4; n++) acc[m][n] = zv;

  const u16x8* Ac = (const u16x8*)A;
  const u16x8* Bc = (const u16x8*)Bt;
  u16x8 ra[4], rb[4];
#pragma unroll
  for (int i = 0; i < 4; i++) {
    ra[i] = Ac[(size_t)(mb * 16 + 0) * 1024 + t + 256 * i];
    rb[i] = Bc[(size_t)(nb * 16 + 0) * 1024 + t + 256 * i];
  }
#pragma unroll
  for (int i = 0; i < 4; i++) {
    int idx = t + 256 * i;
    int row = idx >> 3, ch = idx & 7;
    int sw = (ch ^ (row & 7)) * 8;
    *(u16x8*)(As + row * 64 + sw) = ra[i];
    *(u16x8*)(Bs + row * 64 + sw) = rb[i];
  }
  __syncthreads();

  for (int kt = 0; kt < 16; ++kt) {
    const bool more = (kt + 1) < 16;
    if (more) {
#pragma unroll
      for (int i = 0; i < 4; i++) {
        ra[i] = Ac[(size_t)(mb * 16 + kt + 1) * 1024 + t + 256 * i];
        rb[i] = Bc[(size_t)(nb * 16 + kt + 1) * 1024 + t + 256 * i];
      }
    }
#pragma unroll
    for (int kh = 0; kh < 2; kh++) {
      bf16x8 af[4], bfr[4];
#pragma unroll
      for (int m = 0; m < 4; m++) {
        int row = wm * 64 + m * 16 + c;
        int chr = kh * 4 + g;
        af[m] = asbf(*(const u16x8*)(As + row * 64 + ((chr ^ (row & 7)) * 8)));
      }
#pragma unroll
      for (int n = 0; n < 4; n++) {
        int row = wn * 64 + n * 16 + c;
        int chr = kh * 4 + g;
        bfr[n] = asbf(*(const u16x8*)(Bs + row * 64 + ((chr ^ (row & 7)) * 8)));
      }
#pragma unroll
      for (int m = 0; m < 4; m++)
#pragma unroll
        for (int n = 0; n < 4; n++) acc[m][n] = mfma16(af[m], bfr[n], acc[m][n]);
    }
    if (more) {
      __syncthreads();
#pragma unroll
      for (int i = 0; i < 4; i++) {
        int idx = t + 256 * i;
        int row = idx >> 3, ch = idx & 7;
        int sw = (ch ^ (row & 7)) * 8;
        *(u16x8*)(As + row * 64 + sw) = ra[i];
        *(u16x8*)(Bs + row * 64 + sw) = rb[i];
      }
      __syncthreads();
    }
  }
  // epilogue: C/D layout col=lane&15, row=4*(lane>>4)+r [m89/m91]
  if (zz < 2) {
    // Q/K -> Kt layout: addr = (bh*32+kt)*4096 + ((col&63)>>3)*512 + (R&63)*8 + (col&7)
    u16* Ct = (zz == 0) ? Qt : Kt;
#pragma unroll
    for (int m = 0; m < 4; m++)
#pragma unroll
      for (int n = 0; n < 4; n++) {
        int col = nb * 128 + wn * 64 + n * 16 + c;
        int Rb = mb * 128 + wm * 64 + m * 16 + 4 * g;
        size_t base = ((size_t)((Rb >> 11) * 16 + (col >> 6)) * 32 + ((Rb >> 6) & 31)) * 4096 +
                      ((col & 63) >> 3) * 512 + (size_t)(Rb & 63) * 8 + (col & 7);
#pragma unroll
        for (int r = 0; r < 4; r++)
          Ct[base + (size_t)r * 8] = f2bf(acc[m][n][r] * oscale);
      }
  } else {
    // V -> Vt layout: addr = (bh*32+kt)*4096 + ((R&63)>>3)*512 + (col&63)*8 + (R&7)
#pragma unroll
    for (int m = 0; m < 4; m++)
#pragma unroll
      for (int n = 0; n < 4; n++) {
        int col = nb * 128 + wn * 64 + n * 16 + c;
        int Rb = mb * 128 + wm * 64 + m * 16 + 4 * g;  // 4 consecutive rows from here
        u16x4 ov;
#pragma unroll
        for (int r = 0; r < 4; r++) ov[r] = f2bf(acc[m][n][r]);
        size_t addr = ((size_t)((Rb >> 11) * 16 + (col >> 6)) * 32 + ((Rb >> 6) & 31)) * 4096 +
                      ((Rb & 63) >> 3) * 512 + (size_t)(col & 63) * 8 + (Rb & 7);
        *(u16x4*)(Vt + addr) = ov;
      }
  }
}

// ---------------- 64x128-tile GEMM for the Wo projection (f32 out, r17-verified) ----------------
__global__ __launch_bounds__(256) void gemm_wo(
    const u16* __restrict__ A, const u16* __restrict__ Bt, float* __restrict__ C) {
  __shared__ u16 As[64 * 64];
  __shared__ u16 Bs[128 * 64];
  const int t = threadIdx.x;
  const int lane = t & 63, w = t >> 6;
  const int wm = w >> 1, wn = w & 1;
  const int c = lane & 15, g = lane >> 4;
  const int mb = blockIdx.x, nb = blockIdx.y;

  const f32x4 zv = {0.f, 0.f, 0.f, 0.f};
  f32x4 acc[2][4];
#pragma unroll
  for (int m = 0; m < 2; m++)
#pragma unroll
    for (int n = 0; n < 4; n++) acc[m][n] = zv;

  const u16x8* Ac = (const u16x8*)A;
  const u16x8* Bc = (const u16x8*)Bt;
  const size_t abase = (size_t)(mb >> 1) * 16384 + (size_t)(mb & 1) * 512;
  u16x8 ra[2], rb[4];
#pragma unroll
  for (int i = 0; i < 2; i++) ra[i] = Ac[abase + 0 * 1024 + t + 256 * i];
#pragma unroll
  for (int i = 0; i < 4; i++) rb[i] = Bc[(size_t)(nb * 16 + 0) * 1024 + t + 256 * i];
  {
#pragma unroll
    for (int i = 0; i < 2; i++) {
      int idx = t + 256 * i;
      int row = idx >> 3, ch = idx & 7;
      *(u16x8*)(As + row * 64 + ((ch ^ (row & 7)) * 8)) = ra[i];
    }
#pragma unroll
    for (int i = 0; i < 4; i++) {
      int idx = t + 256 * i;
      int row = idx >> 3, ch = idx & 7;
      *(u16x8*)(Bs + row * 64 + ((ch ^ (row & 7)) * 8)) = rb[i];
    }
  }
  __syncthreads();

  for (int kt = 0; kt < 16; ++kt) {
    const bool more = (kt + 1) < 16;
    if (more) {
#pragma unroll
      for (int i = 0; i < 2; i++) ra[i] = Ac[abase + (size_t)(kt + 1) * 1024 + t + 256 * i];
#pragma unroll
      for (int i = 0; i < 4; i++)
        rb[i] = Bc[(size_t)(nb * 16 + kt + 1) * 1024 + t + 256 * i];
    }
#pragma unroll
    for (int kh = 0; kh < 2; kh++) {
      bf16x8 af[2], bfr[4];
#pragma unroll
      for (int m = 0; m < 2; m++) {
        int row = wm * 32 + m * 16 + c;
        int chr = kh * 4 + g;
        af[m] = asbf(*(const u16x8*)(As + row * 64 + ((chr ^ (row & 7)) * 8)));
      }
#pragma unroll
      for (int n = 0; n < 4; n++) {
        int row = wn * 64 + n * 16 + c;
        int chr = kh * 4 + g;
        bfr[n] = asbf(*(const u16x8*)(Bs + row * 64 + ((chr ^ (row & 7)) * 8)));
      }
#pragma unroll
      for (int m = 0; m < 2; m++)
#pragma unroll
        for (int n = 0; n < 4; n++) acc[m][n] = mfma16(af[m], bfr[n], acc[m][n]);
    }
    if (more) {
      __syncthreads();
#pragma unroll
      for (int i = 0; i < 2; i++) {
        int idx = t + 256 * i;
        int row = idx >> 3, ch = idx & 7;
        *(u16x8*)(As + row * 64 + ((ch ^ (row & 7)) * 8)) = ra[i];
      }
#pragma unroll
      for (int i = 0; i < 4; i++) {
        int idx = t + 256 * i;
        int row = idx >> 3, ch = idx & 7;
        *(u16x8*)(Bs + row * 64 + ((ch ^ (row & 7)) * 8)) = rb[i];
      }
      __syncthreads();
    }
  }
#pragma unroll
  for (int m = 0; m < 2; m++)
#pragma unroll
    for (int n = 0; n < 4; n++)
#pragma unroll
      for (int r = 0; r < 4; r++) {
        int row = mb * 64 + wm * 32 + m * 16 + 4 * g + r;
        int col = nb * 128 + wn * 64 + n * 16 + c;
        C[(size_t)row * 1024 + col] = acc[m][n][r];
      }
}

// ---------------- flash attention: all operands tiled (Qt/Kt/Vt) + KV-split ----------------
__global__ __launch_bounds__(64, 4) void attn_kernel(
    const u16* __restrict__ Qt, const u16* __restrict__ Kt,
    const u16* __restrict__ Vt, const int* __restrict__ vlen,
    u16* __restrict__ O, u16* __restrict__ Opart, float2* __restrict__ mlp) {
  __shared__ u16 ot[32][72];
  const int lane = threadIdx.x;
  const int q = lane & 31, hi = lane >> 5;
  const int bh = blockIdx.y, b = bh >> 4, h = bh & 15;
  const int q0 = blockIdx.x * 32;
  const int nv = vlen[b];
  const int NS = gridDim.z, z = blockIdx.z;

  // Q fragments from the Kt-style Qt tile (2x512B contiguous runs per load)
  bf16x8 qf[4];
  {
    const u16* Qtile = Qt + ((size_t)bh * 32 + (q0 >> 6)) * 4096;
    int qrow = (q0 & 63) + q;
#pragma unroll
    for (int s = 0; s < 4; s++)
      qf[s] = asbf(*(const u16x8*)(Qtile + (2 * s + hi) * 512 + qrow * 8));
  }

  f32x16 o0, o1;
#pragma unroll
  for (int r = 0; r < 16; r++) { o0[r] = 0.f; o1[r] = 0.f; }
  float m = -3.0e38f, l = 0.f;

  const int nt = (nv + 63) >> 6;
  const int chunk = (nt + NS - 1) / NS;
  const int t0 = z * chunk;
  const int t1 = min(nt, t0 + chunk);
  for (int kt = t0; kt < t1; ++kt) {
    const int k0 = kt * 64;
    const u16* Ktile = Kt + ((size_t)bh * 32 + kt) * 4096;
    const u16* Vtile = Vt + ((size_t)bh * 32 + kt) * 4096;
    f32x16 sc[2];
#pragma unroll
    for (int kb = 0; kb < 2; kb++) {
      f32x16 acc;
#pragma unroll
      for (int r = 0; r < 16; r++) acc[r] = 0.f;
#pragma unroll
      for (int s = 0; s < 4; s++) {
        bf16x8 kf = asbf(*(const u16x8*)(Ktile + (2 * s + hi) * 512 + (kb * 32 + q) * 8));
        acc = mfma32(kf, qf[s], acc);
      }
      sc[kb] = acc;
    }
    if (k0 + 64 > nv) {
#pragma unroll
      for (int kb = 0; kb < 2; kb++)
#pragma unroll
        for (int r = 0; r < 16; r++) {
          int key = k0 + kb * 32 + (r & 3) + 8 * (r >> 2) + 4 * hi;
          if (key >= nv) sc[kb][r] = -1e30f;
        }
    }
    float mx[16];
#pragma unroll
    for (int r = 0; r < 16; r++) mx[r] = fmaxf(sc[0][r], sc[1][r]);
#pragma unroll
    for (int st = 8; st > 0; st >>= 1)
#pragma unroll
      for (int r = 0; r < st; r++) mx[r] = fmaxf(mx[r], mx[r + st]);
    float tm = fmaxf(mx[0], __shfl_xor(mx[0], 32));
    if (!__all(tm <= m + 8.f)) {
      float mn = fmaxf(m, tm);
      float al = __expf(m - mn);
#pragma unroll
      for (int r = 0; r < 16; r++) { o0[r] *= al; o1[r] *= al; }
      l *= al;
      m = mn;
    }
    unsigned pw[4][4];
    float s0 = 0.f, s1 = 0.f, s2 = 0.f, s3 = 0.f;
#pragma unroll
    for (int kb = 0; kb < 2; kb++)
#pragma unroll
      for (int hh = 0; hh < 2; hh++)
#pragma unroll
        for (int wi = 0; wi < 4; wi++) {
          float e0 = __expf(sc[kb][hh * 8 + wi * 2] - m);
          float e1 = __expf(sc[kb][hh * 8 + wi * 2 + 1] - m);
          if (wi == 0) s0 += e0 + e1;
          else if (wi == 1) s1 += e0 + e1;
          else if (wi == 2) s2 += e0 + e1;
          else s3 += e0 + e1;
          asm("v_cvt_pk_bf16_f32 %0, %1, %2"
              : "=v"(pw[kb * 2 + hh][wi]) : "v"(e0), "v"(e1));
        }
    float ssum = (s0 + s1) + (s2 + s3);
    ssum += __shfl_xor(ssum, 32);
    l += ssum;
#pragma unroll
    for (int f = 0; f < 4; f++) {
      asm("v_permlane32_swap_b32 %0, %1" : "+v"(pw[f][0]), "+v"(pw[f][2]));
      asm("v_permlane32_swap_b32 %0, %1" : "+v"(pw[f][1]), "+v"(pw[f][3]));
    }
#pragma unroll
    for (int f = 0; f < 4; f++) {
      u32x4 wv = {pw[f][0], pw[f][1], pw[f][2], pw[f][3]};
      bf16x8 pa = __builtin_bit_cast(bf16x8, wv);
      bf16x8 va = asbf(*(const u16x8*)(Vtile + (2 * f + hi) * 512 + q * 8));
      bf16x8 vb = asbf(*(const u16x8*)(Vtile + (2 * f + hi) * 512 + (32 + q) * 8));
      o0 = mfma32(va, pa, o0);
      o1 = mfma32(vb, pa, o1);
    }
  }
  const float scale = (NS == 1) ? (1.f / l) : 1.f;
#pragma unroll
  for (int r = 0; r < 16; r++) {
    const int dh = (r & 3) + 8 * (r >> 2) + 4 * hi;
    ot[q][dh] = f2bf(o0[r] * scale);
    ot[q][32 + dh] = f2bf(o1[r] * scale);
  }
  asm volatile("s_waitcnt lgkmcnt(0)" ::: "memory");
  __builtin_amdgcn_sched_barrier(0);
  if (NS == 1) {
    int R = b * Sdim + q0 + q;
    size_t cellbase = ((size_t)(R >> 7) * 16 + h) * 1024 + (R & 127) * 8 + hi * 4;
#pragma unroll
    for (int j = 0; j < 4; j++)
      ((u16x8*)O)[cellbase + j] = *(const u16x8*)(&ot[q][hi * 32 + j * 8]);
  } else {
    u16* op = Opart + ((size_t)(z * 32 + bh) * Sdim + q0 + q) * 64 + hi * 32;
#pragma unroll
    for (int j = 0; j < 4; j++)
      *(u16x8*)(op + j * 8) = *(const u16x8*)(&ot[q][hi * 32 + j * 8]);
    if (hi == 0)
      mlp[(size_t)(z * 32 + bh) * Sdim + q0 + q] = make_float2(m, l);
  }
}

// ---- combine NS split partials -> O in staging-tiled layout (Wo gemm A) ----
template <int NS>
__global__ __launch_bounds__(256) void attn_combine(
    const u16* __restrict__ Opart, const float2* __restrict__ mlp,
    u16* __restrict__ O) {
  const int t = threadIdx.x;
  const int bh = blockIdx.y, b = bh >> 4, h = bh & 15;
  const int q = blockIdx.x * 32 + (t >> 3);
  const int d0 = (t & 7) * 8;
  float2 ml[NS];
  float M = -3.0e38f;
#pragma unroll
  for (int z = 0; z < NS; z++) {
    ml[z] = mlp[(size_t)(z * 32 + bh) * Sdim + q];
    M = fmaxf(M, ml[z].x);
  }
  float acc[8];
#pragma unroll
  for (int i = 0; i < 8; i++) acc[i] = 0.f;
  float wsum = 0.f;
#pragma unroll
  for (int z = 0; z < NS; z++) {
    float w = __expf(ml[z].x - M);
    wsum += w * ml[z].y;
    u16x8 ov = *(const u16x8*)(Opart + ((size_t)(z * 32 + bh) * Sdim + q) * 64 + d0);
#pragma unroll
    for (int i = 0; i < 8; i++) acc[i] += w * bf2f(ov[i]);
  }
  const float inv = 1.f / wsum;
  u16x8 res;
#pragma unroll
  for (int i = 0; i < 8; i++) res[i] = f2bf(acc[i] * inv);
  int R = b * Sdim + q;
  ((u16x8*)O)[((size_t)(R >> 7) * 16 + h) * 1024 + (R & 127) * 8 + (d0 >> 3)] = res;
}

extern "C" void kernel_launch(void* const* d_in, const int* in_sizes, int n_in,
                              void* d_out, int out_size, void* d_ws, size_t ws_size,
                              hipStream_t stream) {
  const float* x = (const float*)d_in[0];
  const float* Wq = (const float*)d_in[1];
  const float* Wk = (const float*)d_in[2];
  const float* Wv = (const float*)d_in[3];
  const float* Wo = (const float*)d_in[4];
  const int* vl = (const int*)d_in[5];
  float* out = (float*)d_out;

  char* ws = (char*)d_ws;
  const size_t SZ_X = (size_t)Bdim * Sdim * Ddim * sizeof(u16);  // 8 MB
  const size_t SZ_W = (size_t)Ddim * Ddim * sizeof(u16);         // 2 MB
  u16* xt = (u16*)ws; ws += SZ_X;   // staging-tiled x
  u16* WqT = (u16*)ws; ws += SZ_W;  // staging-tiled weights
  u16* WkT = (u16*)ws; ws += SZ_W;
  u16* WvT = (u16*)ws; ws += SZ_W;
  u16* WoT = (u16*)ws; ws += SZ_W;
  u16* Qtb = (u16*)ws; ws += SZ_X;  // attn-tiled Q (Kt layout)
  u16* Ktb = (u16*)ws; ws += SZ_X;  // attn-tiled K
  u16* Vtb = (u16*)ws; ws += SZ_X;  // attn-tiled V^T
  u16* Obt = (u16*)ws; ws += SZ_X;  // staging-tiled attention output

  const size_t PER_SPLIT = (size_t)Bdim * Hdim * Sdim * 64 * sizeof(u16) +
                           (size_t)Bdim * Hdim * Sdim * sizeof(float2);
  size_t used = (size_t)(ws - (char*)d_ws);
  size_t avail = (ws_size > used) ? ws_size - used : 0;
  int NS = (avail >= 4 * PER_SPLIT) ? 4 : (avail >= 2 * PER_SPLIT) ? 2 : 1;
  u16* Opart = (u16*)ws;
  float2* mlp = (float2*)(ws + (size_t)NS * Bdim * Hdim * Sdim * 64 * sizeof(u16));

  cvtx<<<dim3((Bdim * Sdim * Ddim) / (8 * 256)), 256, 0, stream>>>(x, xt);
  transw<<<dim3(32, 32, 4), 256, 0, stream>>>(Wq, Wk, Wv, Wo, WqT, WkT, WvT, WoT);
  // QKV as ONE dispatch, outputs directly in attn-tiled layouts.
  gemm_qkv<<<dim3(32, 24), 256, 0, stream>>>(xt, WqT, WkT, WvT, Qtb, Ktb, Vtb);
  attn_kernel<<<dim3(Sdim / 32, Bdim * Hdim, NS), 64, 0, stream>>>(Qtb, Ktb, Vtb, vl, Obt,
                                                                   Opart, mlp);
  if (NS == 4)
    attn_combine<4><<<dim3(Sdim / 32, Bdim * Hdim), 256, 0, stream>>>(Opart, mlp, Obt);
  else if (NS == 2)
    attn_combine<2><<<dim3(Sdim / 32, Bdim * Hdim), 256, 0, stream>>>(Opart, mlp, Obt);
  gemm_wo<<<dim3(64, 8), 256, 0, stream>>>(Obt, WoT, out);
}